// Round 1
// baseline (1864.454 us; speedup 1.0000x reference)
//
#include <hip/hip_runtime.h>
#include <math.h>

// Problem constants
// B=4 S=1024 D=1024 P=128 H=8 E=16, NT = B*S = 4096, TPOS = 2S-1 = 2047

__device__ __forceinline__ float bf2f(unsigned int u) {
    union { unsigned int i; float f; } x; x.i = (u & 0xffffu) << 16; return x.f;
}
__device__ __forceinline__ unsigned short f2bf(float f) {
    union { float f; unsigned int i; } x; x.f = f;
    unsigned int r = x.i + 0x7fffu + ((x.i >> 16) & 1u);
    return (unsigned short)(r >> 16);
}

// ---------------- Kernel 1: selection scores + top-8 + sigmoid ----------------
__global__ __launch_bounds__(256) void k_sel(const float* __restrict__ curr,
                                             const float* __restrict__ sel_dst,
                                             float* __restrict__ selval,
                                             int* __restrict__ selidx) {
    __shared__ float row[1024];
    __shared__ float sel[16];
    const int token = blockIdx.x;
    const int t = threadIdx.x;
    ((float4*)row)[t] = ((const float4*)(curr + (size_t)token * 1024))[t];
    __syncthreads();
    const int wv = t >> 6, lane = t & 63;
    for (int e0 = 0; e0 < 4; ++e0) {
        const int e = wv * 4 + e0;
        const float* w = sel_dst + e * 1024;
        float p = 0.f;
        for (int i = lane; i < 1024; i += 64) p += row[i] * w[i];
        for (int off = 32; off; off >>= 1) p += __shfl_down(p, off, 64);
        if (lane == 0) sel[e] = p;
    }
    __syncthreads();
    if (t == 0) {
        float v[16];
#pragma unroll
        for (int e = 0; e < 16; ++e) v[e] = sel[e];
#pragma unroll
        for (int r = 0; r < 8; ++r) {
            int bi = 0; float bv = v[0];
#pragma unroll
            for (int e = 1; e < 16; ++e) { if (v[e] > bv) { bv = v[e]; bi = e; } }
            selidx[token * 8 + r] = bi;
            selval[token * 8 + r] = 1.f / (1.f + __expf(-bv));
            v[bi] = -INFINITY;
        }
    }
}

// ---------------- Kernel 2: kv = attend_to @ data_to_kv ; k *= sc ----------------
__global__ __launch_bounds__(256) void k_kv(const float* __restrict__ attend,
                                            const float* __restrict__ w_kv,
                                            const float* __restrict__ scale,
                                            float* __restrict__ kmat,
                                            float* __restrict__ vmat) {
    __shared__ float a[16][1024];  // 64 KB
    const int t = threadIdx.x;
    const int tok0 = blockIdx.x * 16;
    {
        const float4* src = (const float4*)(attend + (size_t)tok0 * 1024);
        float4* dst = (float4*)&a[0][0];
#pragma unroll
        for (int i = 0; i < 16; ++i) dst[t + 256 * i] = src[t + 256 * i];
    }
    __syncthreads();
    const float sc = sqrtf(scale[0]);
    float acc[16];
#pragma unroll
    for (int k = 0; k < 16; ++k) acc[k] = 0.f;
    const int c = t;  // 0..255
    for (int i = 0; i < 1024; ++i) {
        const float w = w_kv[i * 256 + c];
#pragma unroll
        for (int k = 0; k < 16; ++k) acc[k] += a[k][i] * w;
    }
    if (c < 128) {
#pragma unroll
        for (int k = 0; k < 16; ++k) kmat[(size_t)(tok0 + k) * 128 + c] = acc[k] * sc;
    } else {
        const int cc = c - 128;
#pragma unroll
        for (int k = 0; k < 16; ++k) vmat[(size_t)(tok0 + k) * 128 + cc] = acc[k];
    }
}

// ---------------- Kernel 3: k_pos = (sinusoidal pemb) @ pos_to_pk^T * sc ----------------
__global__ __launch_bounds__(128) void k_kpos(const float* __restrict__ pos_pk,
                                              const float* __restrict__ scale,
                                              float* __restrict__ kposm) {
    __shared__ float pe[8][1024];  // 32 KB
    const int t = threadIdx.x;     // 128 threads
    const int t0 = blockIdx.x * 8;
    const float c1 = -logf(10000.f) / 1024.f;
    for (int rr = 0; rr < 8; ++rr) {
        int tp = t0 + rr; if (tp > 2046) tp = 2046;
        const float pos = (float)(tp - 1023);
        for (int i = t; i < 512; i += 128) {
            const float dv = expf((2.f * (float)i) * c1);
            const float ang = pos * dv;
            pe[rr][2 * i]     = sinf(ang);
            pe[rr][2 * i + 1] = cosf(ang);
        }
    }
    __syncthreads();
    const float sc = sqrtf(scale[0]);
    float acc[8];
#pragma unroll
    for (int r = 0; r < 8; ++r) acc[r] = 0.f;
    const float* w = pos_pk + (size_t)t * 1024;  // row t of pos_to_pk (PROJ x 1024)
    for (int d = 0; d < 1024; ++d) {
        const float wv = w[d];
#pragma unroll
        for (int r = 0; r < 8; ++r) acc[r] += pe[r][d] * wv;
    }
#pragma unroll
    for (int r = 0; r < 8; ++r) {
        const int tp = t0 + r;
        if (tp < 2047) kposm[(size_t)tp * 128 + t] = acc[r] * sc;
    }
}

// ---------------- Kernel 4: q_all = curr @ data_to_q[e] * sc  (bf16 out) ----------------
__global__ __launch_bounds__(256) void k_qall(const float* __restrict__ curr,
                                              const float* __restrict__ w_q,
                                              const float* __restrict__ scale,
                                              unsigned short* __restrict__ qall) {
    __shared__ float atile[64][64];    // 16 KB
    __shared__ float wtile[64][128];   // 32 KB
    const int t = threadIdx.x;
    const int tok0 = blockIdx.x * 64;
    const int e = blockIdx.y;
    const float* w_e = w_q + (size_t)e * 1024 * 128;
    float acc[8][4];
#pragma unroll
    for (int k = 0; k < 8; ++k) { acc[k][0] = acc[k][1] = acc[k][2] = acc[k][3] = 0.f; }
    const int cr = t & 31;   // col group: cols cr*4..cr*4+3
    const int rr = t >> 5;   // row base: rows rr + 8k
    for (int i0 = 0; i0 < 1024; i0 += 64) {
        __syncthreads();
#pragma unroll
        for (int l = 0; l < 4; ++l) {
            const int idx = t + 256 * l;
            const int r = idx >> 4, cc = idx & 15;
            ((float4*)&atile[r][0])[cc] = ((const float4*)(curr + (size_t)(tok0 + r) * 1024 + i0))[cc];
        }
#pragma unroll
        for (int l = 0; l < 8; ++l) {
            const int idx = t + 256 * l;
            const int r = idx >> 5, cc = idx & 31;
            ((float4*)&wtile[r][0])[cc] = ((const float4*)(w_e + (size_t)(i0 + r) * 128))[cc];
        }
        __syncthreads();
        for (int i = 0; i < 64; ++i) {
            const float4 b4 = ((const float4*)&wtile[i][0])[cr];
#pragma unroll
            for (int k = 0; k < 8; ++k) {
                const float av = atile[rr + 8 * k][i];
                acc[k][0] += av * b4.x; acc[k][1] += av * b4.y;
                acc[k][2] += av * b4.z; acc[k][3] += av * b4.w;
            }
        }
    }
    const float sc = sqrtf(scale[0]);
#pragma unroll
    for (int k = 0; k < 8; ++k) {
        const size_t base = (size_t)(tok0 + rr + 8 * k) * 2048 + e * 128 + cr * 4;
        uint2 o;
        o.x = (unsigned int)f2bf(acc[k][0] * sc) | ((unsigned int)f2bf(acc[k][1] * sc) << 16);
        o.y = (unsigned int)f2bf(acc[k][2] * sc) | ((unsigned int)f2bf(acc[k][3] * sc) << 16);
        *(uint2*)(qall + base) = o;
    }
}

// ---------------- Kernel 5: flash attention with relative-position band ----------------
// block = (b, h, 16-row s-tile); logits: att[s,j] = q[s] . (k[j] + kpos[j-s+1023])
__global__ __launch_bounds__(256) void k_attn(const unsigned short* __restrict__ qall,
                                              const float* __restrict__ kmat,
                                              const float* __restrict__ vmat,
                                              const float* __restrict__ kposm,
                                              const int* __restrict__ selidx,
                                              const float* __restrict__ selval,
                                              unsigned short* __restrict__ zall) {
    __shared__ float q_lds[16][128];          // 8 KB
    __shared__ float kT[128][33];             // 16.5 KB transposed
    __shared__ unsigned short kpT[128][49];   // 12.25 KB transposed bf16
    __shared__ float v_lds[32][128];          // 16 KB
    __shared__ float prob[16][33];            // 2 KB
    __shared__ float m_s[16], l_s[16], al_s[16];

    const int t = threadIdx.x;
    const int st = blockIdx.x & 63;
    const int bh = blockIdx.x >> 6;
    const int b = bh >> 3, h = bh & 7;
    const int s0 = st * 16;

    const int s_a = t >> 4;           // acc-phase row
    const int p_a = (t & 15) * 8;     // acc-phase col base
    {
        const int token = b * 1024 + s0 + s_a;
        const int e = selidx[token * 8 + h];
        const uint4 u = *(const uint4*)(qall + (size_t)token * 2048 + e * 128 + p_a);
        float* qp = &q_lds[s_a][p_a];
        qp[0] = bf2f(u.x); qp[1] = bf2f(u.x >> 16);
        qp[2] = bf2f(u.y); qp[3] = bf2f(u.y >> 16);
        qp[4] = bf2f(u.z); qp[5] = bf2f(u.z >> 16);
        qp[6] = bf2f(u.w); qp[7] = bf2f(u.w >> 16);
    }
    if (t < 16) { m_s[t] = -INFINITY; l_s[t] = 0.f; }

    float acc[8];
#pragma unroll
    for (int i = 0; i < 8; ++i) acc[i] = 0.f;

    const int s1 = t >> 5;    // logit rows s1 and s1+8
    const int jj = t & 31;

    for (int j0 = 0; j0 < 1024; j0 += 32) {
        __syncthreads();
        // stage k (transposed) and v
        {
            const int jr = t >> 3;
            const int p0 = (t & 7) * 16;
            const float* srck = kmat + (size_t)(b * 1024 + j0 + jr) * 128 + p0;
            const float* srcv = vmat + (size_t)(b * 1024 + j0 + jr) * 128 + p0;
#pragma unroll
            for (int i = 0; i < 16; i += 4) {
                const float4 f = *(const float4*)(srck + i);
                kT[p0 + i + 0][jr] = f.x; kT[p0 + i + 1][jr] = f.y;
                kT[p0 + i + 2][jr] = f.z; kT[p0 + i + 3][jr] = f.w;
            }
#pragma unroll
            for (int i = 0; i < 16; i += 4) {
                *(float4*)&v_lds[jr][p0 + i] = *(const float4*)(srcv + i);
            }
        }
        // stage 47 kpos diagonals (transposed, bf16)
        {
            const int tb = j0 - s0 + 1008;  // 1023 - 15
            for (int idx = t; idx < 47 * 128; idx += 256) {
                const int dd = idx >> 7, p = idx & 127;
                kpT[p][dd] = f2bf(kposm[(size_t)(tb + dd) * 128 + p]);
            }
        }
        __syncthreads();
        // logits for pairs (s1, jj) and (s1+8, jj)
        float lg1 = 0.f, lg2 = 0.f;
        const int dd1 = jj - s1 + 15;
        const int dd2 = dd1 - 8;
        for (int p = 0; p < 128; p += 4) {
            const float4 qa = *(const float4*)&q_lds[s1][p];
            const float4 qb = *(const float4*)&q_lds[s1 + 8][p];
            const float k0 = kT[p + 0][jj], k1 = kT[p + 1][jj];
            const float k2 = kT[p + 2][jj], k3 = kT[p + 3][jj];
            lg1 += qa.x * (k0 + bf2f(kpT[p + 0][dd1])) + qa.y * (k1 + bf2f(kpT[p + 1][dd1]))
                 + qa.z * (k2 + bf2f(kpT[p + 2][dd1])) + qa.w * (k3 + bf2f(kpT[p + 3][dd1]));
            lg2 += qb.x * (k0 + bf2f(kpT[p + 0][dd2])) + qb.y * (k1 + bf2f(kpT[p + 1][dd2]))
                 + qb.z * (k2 + bf2f(kpT[p + 2][dd2])) + qb.w * (k3 + bf2f(kpT[p + 3][dd2]));
        }
        // online softmax update (32-lane row groups)
        float mx1 = lg1, mx2 = lg2;
#pragma unroll
        for (int off = 16; off; off >>= 1) {
            mx1 = fmaxf(mx1, __shfl_xor(mx1, off, 64));
            mx2 = fmaxf(mx2, __shfl_xor(mx2, off, 64));
        }
        const float mo1 = m_s[s1], mo2 = m_s[s1 + 8];
        const float mn1 = fmaxf(mo1, mx1), mn2 = fmaxf(mo2, mx2);
        const float p1 = __expf(lg1 - mn1), p2 = __expf(lg2 - mn2);
        float r1 = p1, r2 = p2;
#pragma unroll
        for (int off = 16; off; off >>= 1) {
            r1 += __shfl_xor(r1, off, 64);
            r2 += __shfl_xor(r2, off, 64);
        }
        prob[s1][jj] = p1; prob[s1 + 8][jj] = p2;
        if (jj == 0) {
            const float a1 = __expf(mo1 - mn1), a2 = __expf(mo2 - mn2);
            al_s[s1] = a1; al_s[s1 + 8] = a2;
            m_s[s1] = mn1; m_s[s1 + 8] = mn2;
            l_s[s1] = l_s[s1] * a1 + r1; l_s[s1 + 8] = l_s[s1 + 8] * a2 + r2;
        }
        __syncthreads();
        // accumulate O
        const float alpha = al_s[s_a];
#pragma unroll
        for (int i = 0; i < 8; ++i) acc[i] *= alpha;
        for (int j = 0; j < 32; ++j) {
            const float pr = prob[s_a][j];
            const float4 va = *(const float4*)&v_lds[j][p_a];
            const float4 vb = *(const float4*)&v_lds[j][p_a + 4];
            acc[0] += pr * va.x; acc[1] += pr * va.y; acc[2] += pr * va.z; acc[3] += pr * va.w;
            acc[4] += pr * vb.x; acc[5] += pr * vb.y; acc[6] += pr * vb.z; acc[7] += pr * vb.w;
        }
    }
    __syncthreads();
    // epilogue: z[token][e*128 + p] = sigmoid_gate * O / l   (bf16, scattered to expert slot)
    {
        const float linv = 1.f / l_s[s_a];
        const int token = b * 1024 + s0 + s_a;
        const int e = selidx[token * 8 + h];
        const float g = selval[token * 8 + h] * linv;
        unsigned short* dst = zall + (size_t)token * 2048 + e * 128 + p_a;
        uint4 o;
        o.x = (unsigned)f2bf(acc[0] * g) | ((unsigned)f2bf(acc[1] * g) << 16);
        o.y = (unsigned)f2bf(acc[2] * g) | ((unsigned)f2bf(acc[3] * g) << 16);
        o.z = (unsigned)f2bf(acc[4] * g) | ((unsigned)f2bf(acc[5] * g) << 16);
        o.w = (unsigned)f2bf(acc[6] * g) | ((unsigned)f2bf(acc[7] * g) << 16);
        *(uint4*)dst = o;
    }
}

// ---------------- Kernel 6: out = z(4096x2048,bf16) @ out_proj(2048x1024) ----------------
__global__ __launch_bounds__(256) void k_out(const unsigned short* __restrict__ zall,
                                             const float* __restrict__ w_out,
                                             float* __restrict__ out) {
    __shared__ float ztile[64][64];    // 16 KB
    __shared__ float wtile[64][128];   // 32 KB
    const int t = threadIdx.x;
    const int tok0 = blockIdx.x * 64;
    const int o0 = blockIdx.y * 128;
    float acc[8][4];
#pragma unroll
    for (int k = 0; k < 8; ++k) { acc[k][0] = acc[k][1] = acc[k][2] = acc[k][3] = 0.f; }
    const int cr = t & 31, rr = t >> 5;
    for (int i0 = 0; i0 < 2048; i0 += 64) {
        __syncthreads();
        {
            const int r = t >> 2, c0 = (t & 3) * 16;
            const uint4* src = (const uint4*)(zall + (size_t)(tok0 + r) * 2048 + i0 + c0);
            const uint4 u0 = src[0], u1 = src[1];
            float* zp = &ztile[r][c0];
            zp[0]  = bf2f(u0.x); zp[1]  = bf2f(u0.x >> 16);
            zp[2]  = bf2f(u0.y); zp[3]  = bf2f(u0.y >> 16);
            zp[4]  = bf2f(u0.z); zp[5]  = bf2f(u0.z >> 16);
            zp[6]  = bf2f(u0.w); zp[7]  = bf2f(u0.w >> 16);
            zp[8]  = bf2f(u1.x); zp[9]  = bf2f(u1.x >> 16);
            zp[10] = bf2f(u1.y); zp[11] = bf2f(u1.y >> 16);
            zp[12] = bf2f(u1.z); zp[13] = bf2f(u1.z >> 16);
            zp[14] = bf2f(u1.w); zp[15] = bf2f(u1.w >> 16);
        }
#pragma unroll
        for (int l = 0; l < 8; ++l) {
            const int idx = t + 256 * l;
            const int r = idx >> 5, cc = idx & 31;
            ((float4*)&wtile[r][0])[cc] = ((const float4*)(w_out + (size_t)(i0 + r) * 1024 + o0))[cc];
        }
        __syncthreads();
        for (int i = 0; i < 64; ++i) {
            const float4 b4 = ((const float4*)&wtile[i][0])[cr];
#pragma unroll
            for (int k = 0; k < 8; ++k) {
                const float av = ztile[rr + 8 * k][i];
                acc[k][0] += av * b4.x; acc[k][1] += av * b4.y;
                acc[k][2] += av * b4.z; acc[k][3] += av * b4.w;
            }
        }
    }
#pragma unroll
    for (int k = 0; k < 8; ++k) {
        float4 o4; o4.x = acc[k][0]; o4.y = acc[k][1]; o4.z = acc[k][2]; o4.w = acc[k][3];
        *(float4*)(out + (size_t)(tok0 + rr + 8 * k) * 1024 + o0 + cr * 4) = o4;
    }
}

extern "C" void kernel_launch(void* const* d_in, const int* in_sizes, int n_in,
                              void* d_out, int out_size, void* d_ws, size_t ws_size,
                              hipStream_t stream) {
    const float* curr    = (const float*)d_in[0];  // (4,1024,1024)
    const float* attend  = (const float*)d_in[1];  // (4,1024,1024)
    const float* w_q     = (const float*)d_in[2];  // (16,1024,128)
    const float* w_kv    = (const float*)d_in[3];  // (1024,256)
    const float* w_out   = (const float*)d_in[4];  // (16,128,1024)
    const float* pos_pk  = (const float*)d_in[5];  // (128,1024)
    const float* sel_dst = (const float*)d_in[6];  // (16,1024)
    const float* scale   = (const float*)d_in[7];  // (1,)
    float* out = (float*)d_out;

    float* ws = (float*)d_ws;
    float* kposm  = ws;                         // 2047*128 -> 262144 floats
    float* kmat   = ws + 262144;                // 4096*128
    float* vmat   = kmat + 524288;              // 4096*128
    float* selval = vmat + 524288;              // 4096*8
    int*   selidx = (int*)(selval + 32768);     // 4096*8
    unsigned short* qall = (unsigned short*)(selidx + 32768);  // 4096*2048 bf16
    unsigned short* zall = qall + (size_t)4096 * 2048;         // 4096*2048 bf16

    hipMemsetAsync(zall, 0, (size_t)4096 * 2048 * sizeof(unsigned short), stream);
    k_sel<<<4096, 256, 0, stream>>>(curr, sel_dst, selval, selidx);
    k_kv<<<256, 256, 0, stream>>>(attend, w_kv, scale, kmat, vmat);
    k_kpos<<<256, 128, 0, stream>>>(pos_pk, scale, kposm);
    k_qall<<<dim3(64, 16), 256, 0, stream>>>(curr, w_q, scale, qall);
    k_attn<<<2048, 256, 0, stream>>>(qall, kmat, vmat, kposm, selidx, selval, zall);
    k_out<<<dim3(64, 8), 256, 0, stream>>>(zall, w_out, out);
}

// Round 2
// 777.375 us; speedup vs baseline: 2.3984x; 2.3984x over previous
//
#include <hip/hip_runtime.h>
#include <math.h>

// B=4 S=1024 D=1024 P=128 H=8 E=16, NT=4096, TPOS=2047

typedef __attribute__((ext_vector_type(8))) short short8;
typedef __attribute__((ext_vector_type(4))) float floatx4;

__device__ __forceinline__ float bf2f(unsigned int u) {
    union { unsigned int i; float f; } x; x.i = (u & 0xffffu) << 16; return x.f;
}
__device__ __forceinline__ unsigned short f2bf(float f) {
    union { float f; unsigned int i; } x; x.f = f;
    unsigned int r = x.i + 0x7fffu + ((x.i >> 16) & 1u);
    return (unsigned short)(r >> 16);
}

// async global->LDS: wave-uniform LDS base, lane data lands at base + lane*16
__device__ __forceinline__ void gload16(const void* g, void* l) {
    __builtin_amdgcn_global_load_lds(
        (const __attribute__((address_space(1))) unsigned int*)(uintptr_t)g,
        (__attribute__((address_space(3))) unsigned int*)(uintptr_t)l,
        16, 0, 0);
}

// ---------------- Kernel 1: selection scores + top-8 + sigmoid ----------------
__global__ __launch_bounds__(256) void k_sel(const float* __restrict__ curr,
                                             const float* __restrict__ sel_dst,
                                             float* __restrict__ selval,
                                             int* __restrict__ selidx) {
    __shared__ float row[1024];
    __shared__ float sel[16];
    const int token = blockIdx.x;
    const int t = threadIdx.x;
    ((float4*)row)[t] = ((const float4*)(curr + (size_t)token * 1024))[t];
    __syncthreads();
    const int wv = t >> 6, lane = t & 63;
    for (int e0 = 0; e0 < 4; ++e0) {
        const int e = wv * 4 + e0;
        const float* w = sel_dst + e * 1024;
        float p = 0.f;
        for (int i = lane; i < 1024; i += 64) p += row[i] * w[i];
        for (int off = 32; off; off >>= 1) p += __shfl_down(p, off, 64);
        if (lane == 0) sel[e] = p;
    }
    __syncthreads();
    if (t == 0) {
        float v[16];
#pragma unroll
        for (int e = 0; e < 16; ++e) v[e] = sel[e];
#pragma unroll
        for (int r = 0; r < 8; ++r) {
            int bi = 0; float bv = v[0];
#pragma unroll
            for (int e = 1; e < 16; ++e) { if (v[e] > bv) { bv = v[e]; bi = e; } }
            selidx[token * 8 + r] = bi;
            selval[token * 8 + r] = 1.f / (1.f + __expf(-bv));
            v[bi] = -INFINITY;
        }
    }
}

// ---------------- Kernel 2: kv = attend_to @ data_to_kv -> K/V B-fragment layouts ----------------
// kfragg[b][jt(64)][c(4)][lane(64)][8]  : K[j][p] -> jt=j>>4, c=p>>5, lane=((p&31)>>3)*16+(j&15), idx=p&7
// vfragg[b][jg(32)][nt(8)][lane(64)][8] : V[j][p] -> jg=j>>5, nt=p>>4, lane=((j&31)>>3)*16+(p&15), idx=j&7
__global__ __launch_bounds__(256) void k_kv(const float* __restrict__ attend,
                                            const float* __restrict__ w_kv,
                                            const float* __restrict__ scale,
                                            unsigned short* __restrict__ kfragg,
                                            unsigned short* __restrict__ vfragg) {
    __shared__ float a[16][1024];  // 64 KB
    const int t = threadIdx.x;
    const int tok0 = blockIdx.x * 16;
    {
        const float4* src = (const float4*)(attend + (size_t)tok0 * 1024);
        float4* dst = (float4*)&a[0][0];
#pragma unroll
        for (int i = 0; i < 16; ++i) dst[t + 256 * i] = src[t + 256 * i];
    }
    __syncthreads();
    const float sc = sqrtf(scale[0]);
    float acc[16];
#pragma unroll
    for (int k = 0; k < 16; ++k) acc[k] = 0.f;
    const int c = t;  // 0..255
    for (int i = 0; i < 1024; ++i) {
        const float w = w_kv[i * 256 + c];
#pragma unroll
        for (int k = 0; k < 16; ++k) acc[k] += a[k][i] * w;
    }
    if (c < 128) {
        const int ch = c >> 5, pr = c & 31;
        const int laneB = (pr >> 3) * 16, idx = pr & 7;
#pragma unroll
        for (int k = 0; k < 16; ++k) {
            const int tok = tok0 + k, bb = tok >> 10, j = tok & 1023;
            const size_t addr = ((((size_t)bb * 64 + (j >> 4)) * 4 + ch) * 64 + laneB + (j & 15)) * 8 + idx;
            kfragg[addr] = f2bf(acc[k] * sc);
        }
    } else {
        const int p = c - 128, nt = p >> 4, pm = p & 15;
#pragma unroll
        for (int k = 0; k < 16; ++k) {
            const int tok = tok0 + k, bb = tok >> 10, j = tok & 1023, jg = j >> 5, jr = j & 31;
            const size_t addr = ((((size_t)bb * 32 + jg) * 8 + nt) * 64 + (jr >> 3) * 16 + pm) * 8 + (jr & 7);
            vfragg[addr] = f2bf(acc[k]);
        }
    }
}

// ---------------- Kernel 3: k_pos -> B-fragment layout (bf16) ----------------
// kposfg[g(128)][c(4)][lane(64)][8] : kpos[d][p] -> g=d>>4, c=p>>5, lane=((p&31)>>3)*16+(d&15), idx=p&7
// row d=2047 (pad) written as zeros
__global__ __launch_bounds__(128) void k_kpos(const float* __restrict__ pos_pk,
                                              const float* __restrict__ scale,
                                              unsigned short* __restrict__ kposfg) {
    __shared__ float pe[8][1024];  // 32 KB
    const int t = threadIdx.x;     // 128 threads
    const int t0 = blockIdx.x * 8;
    const float c1 = -logf(10000.f) / 1024.f;
    for (int rr = 0; rr < 8; ++rr) {
        int tp = t0 + rr; if (tp > 2046) tp = 2046;
        const float pos = (float)(tp - 1023);
        for (int i = t; i < 512; i += 128) {
            const float dv = expf((2.f * (float)i) * c1);
            const float ang = pos * dv;
            pe[rr][2 * i]     = sinf(ang);
            pe[rr][2 * i + 1] = cosf(ang);
        }
    }
    __syncthreads();
    const float sc = sqrtf(scale[0]);
    float acc[8];
#pragma unroll
    for (int r = 0; r < 8; ++r) acc[r] = 0.f;
    const float* w = pos_pk + (size_t)t * 1024;  // row p=t of pos_to_pk
    for (int d = 0; d < 1024; ++d) {
        const float wv = w[d];
#pragma unroll
        for (int r = 0; r < 8; ++r) acc[r] += pe[r][d] * wv;
    }
    const int ch = t >> 5, pr = t & 31;
#pragma unroll
    for (int r = 0; r < 8; ++r) {
        const int tp = t0 + r;
        if (tp >= 2048) continue;
        const float v = (tp <= 2046) ? acc[r] * sc : 0.f;
        const size_t addr = (((size_t)(tp >> 4) * 4 + ch) * 64 + (pr >> 3) * 16 + (tp & 15)) * 8 + (pr & 7);
        kposfg[addr] = f2bf(v);
    }
}

// ---------------- Kernel 4: q_all = curr @ data_to_q[e] * sc  (bf16 out) ----------------
__global__ __launch_bounds__(256) void k_qall(const float* __restrict__ curr,
                                              const float* __restrict__ w_q,
                                              const float* __restrict__ scale,
                                              unsigned short* __restrict__ qall) {
    __shared__ float atile[64][64];    // 16 KB
    __shared__ float wtile[64][128];   // 32 KB
    const int t = threadIdx.x;
    const int tok0 = blockIdx.x * 64;
    const int e = blockIdx.y;
    const float* w_e = w_q + (size_t)e * 1024 * 128;
    float acc[8][4];
#pragma unroll
    for (int k = 0; k < 8; ++k) { acc[k][0] = acc[k][1] = acc[k][2] = acc[k][3] = 0.f; }
    const int cr = t & 31;
    const int rr = t >> 5;
    for (int i0 = 0; i0 < 1024; i0 += 64) {
        __syncthreads();
#pragma unroll
        for (int l = 0; l < 4; ++l) {
            const int idx = t + 256 * l;
            const int r = idx >> 4, cc = idx & 15;
            ((float4*)&atile[r][0])[cc] = ((const float4*)(curr + (size_t)(tok0 + r) * 1024 + i0))[cc];
        }
#pragma unroll
        for (int l = 0; l < 8; ++l) {
            const int idx = t + 256 * l;
            const int r = idx >> 5, cc = idx & 31;
            ((float4*)&wtile[r][0])[cc] = ((const float4*)(w_e + (size_t)(i0 + r) * 128))[cc];
        }
        __syncthreads();
        for (int i = 0; i < 64; ++i) {
            const float4 b4 = ((const float4*)&wtile[i][0])[cr];
#pragma unroll
            for (int k = 0; k < 8; ++k) {
                const float av = atile[rr + 8 * k][i];
                acc[k][0] += av * b4.x; acc[k][1] += av * b4.y;
                acc[k][2] += av * b4.z; acc[k][3] += av * b4.w;
            }
        }
    }
    const float sc = sqrtf(scale[0]);
#pragma unroll
    for (int k = 0; k < 8; ++k) {
        const size_t base = (size_t)(tok0 + rr + 8 * k) * 2048 + e * 128 + cr * 4;
        uint2 o;
        o.x = (unsigned int)f2bf(acc[k][0] * sc) | ((unsigned int)f2bf(acc[k][1] * sc) << 16);
        o.y = (unsigned int)f2bf(acc[k][2] * sc) | ((unsigned int)f2bf(acc[k][3] * sc) << 16);
        *(uint2*)(qall + base) = o;
    }
}

// ---------------- Kernel 5: MFMA flash attention with relative-position band ----------------
// grid: (b,h,s-tile of 64). 4 waves, wave w owns 16 s-rows [s0+16w, s0+16w+15].
__global__ __launch_bounds__(256) void k_attn(const unsigned short* __restrict__ qall,
                                              const unsigned short* __restrict__ kfragg,
                                              const unsigned short* __restrict__ vfragg,
                                              const unsigned short* __restrict__ kposfg,
                                              const int* __restrict__ selidx,
                                              const float* __restrict__ selval,
                                              unsigned short* __restrict__ zall) {
    __shared__ __align__(16) unsigned short kfrag[2][4][512];   // 8 KB
    __shared__ __align__(16) unsigned short vfrag[8][512];      // 8 KB
    __shared__ __align__(16) unsigned short kpfrag[6][4][512];  // 24 KB
    __shared__ __align__(16) float spos[4][16][52];             // 13.3 KB
    __shared__ __align__(16) unsigned short plds[4][16][56];    // 7 KB

    const int t = threadIdx.x;
    const int w = t >> 6, lane = t & 63;
    const int st = blockIdx.x & 15;
    const int bh = blockIdx.x >> 4;
    const int b = bh >> 3, h = bh & 7;
    const int s0 = st * 64;
    const int lq = lane >> 4;   // quad
    const int lm = lane & 15;

    // Q A-fragments: A[m=lm][k = c*32 + lq*8 + i]
    short8 qf[4];
    {
        const int token = b * 1024 + s0 + 16 * w + lm;
        const int e = selidx[token * 8 + h];
        const unsigned short* qb = qall + (size_t)token * 2048 + e * 128 + lq * 8;
#pragma unroll
        for (int c = 0; c < 4; ++c) qf[c] = *(const short8*)(qb + c * 32);
    }

    floatx4 acc[8];
#pragma unroll
    for (int nt = 0; nt < 8; ++nt) acc[nt] = (floatx4){0.f, 0.f, 0.f, 0.f};
    float m_r[4], l_r[4];
#pragma unroll
    for (int r = 0; r < 4; ++r) { m_r[r] = -INFINITY; l_r[r] = 0.f; }

    for (int j0 = 0; j0 < 1024; j0 += 32) {
        __syncthreads();   // previous iteration's fragment reads complete
        const int G0 = (j0 - s0 + 960) >> 4;   // base kpos subtile (always in [0,122])
        if (w < 3) {
#pragma unroll
            for (int s2 = 0; s2 < 2; ++s2) {
                const int stile = 2 * w + s2;
#pragma unroll
                for (int c = 0; c < 4; ++c)
                    gload16(kposfg + (((size_t)(G0 + stile) * 4 + c) * 64 + lane) * 8,
                            &kpfrag[stile][c][0]);
            }
        } else {
#pragma unroll
            for (int jt = 0; jt < 2; ++jt)
#pragma unroll
                for (int c = 0; c < 4; ++c)
                    gload16(kfragg + ((((size_t)b * 64 + (j0 >> 4) + jt) * 4 + c) * 64 + lane) * 8,
                            &kfrag[jt][c][0]);
#pragma unroll
            for (int nt = 0; nt < 8; ++nt)
                gload16(vfragg + ((((size_t)b * 32 + (j0 >> 5)) * 8 + nt) * 64 + lane) * 8,
                        &vfrag[nt][0]);
        }
        __syncthreads();   // vmcnt drained -> fragments visible

        // S_k = Q @ K^T  (two 16x16 j-subtiles)
        floatx4 sk0 = {0.f, 0.f, 0.f, 0.f}, sk1 = {0.f, 0.f, 0.f, 0.f};
#pragma unroll
        for (int c = 0; c < 4; ++c) {
            sk0 = __builtin_amdgcn_mfma_f32_16x16x32_bf16(qf[c], *(const short8*)&kfrag[0][c][lane * 8], sk0, 0, 0, 0);
            sk1 = __builtin_amdgcn_mfma_f32_16x16x32_bf16(qf[c], *(const short8*)&kfrag[1][c][lane * 8], sk1, 0, 0, 0);
        }
        // S_pos: wave w uses kpos subtile slots (3-w)..(5-w); window base W_w s.t. cc = 15 + jj - ss
#pragma unroll
        for (int sp3 = 0; sp3 < 3; ++sp3) {
            floatx4 spv = {0.f, 0.f, 0.f, 0.f};
            const int slot = 3 - w + sp3;
#pragma unroll
            for (int c = 0; c < 4; ++c)
                spv = __builtin_amdgcn_mfma_f32_16x16x32_bf16(qf[c], *(const short8*)&kpfrag[slot][c][lane * 8], spv, 0, 0, 0);
#pragma unroll
            for (int r = 0; r < 4; ++r)
                spos[w][lq * 4 + r][sp3 * 16 + lm] = spv[r];
        }
        asm volatile("" ::: "memory");   // per-wave LDS RAW: keep program order

        // gather + combine + online softmax (C-layout rows lq*4+r, col lm)
        float alpha[4];
#pragma unroll
        for (int r = 0; r < 4; ++r) {
            const int row = lq * 4 + r;
            const float v0 = sk0[r] + spos[w][row][15 + lm - row];
            const float v1 = sk1[r] + spos[w][row][31 + lm - row];
            float mx = fmaxf(v0, v1);
            mx = fmaxf(mx, __shfl_xor(mx, 1, 64));
            mx = fmaxf(mx, __shfl_xor(mx, 2, 64));
            mx = fmaxf(mx, __shfl_xor(mx, 4, 64));
            mx = fmaxf(mx, __shfl_xor(mx, 8, 64));
            const float mn = fmaxf(m_r[r], mx);
            const float al = __expf(m_r[r] - mn);
            m_r[r] = mn;
            const float p0 = __expf(v0 - mn), p1 = __expf(v1 - mn);
            float rs = p0 + p1;
            rs += __shfl_xor(rs, 1, 64);
            rs += __shfl_xor(rs, 2, 64);
            rs += __shfl_xor(rs, 4, 64);
            rs += __shfl_xor(rs, 8, 64);
            l_r[r] = l_r[r] * al + rs;
            alpha[r] = al;
            plds[w][row][lm]      = f2bf(p0);
            plds[w][row][16 + lm] = f2bf(p1);
        }
        asm volatile("" ::: "memory");
        // P -> A-fragment; AV accumulate
        const short8 pf = *(const short8*)&plds[w][lm][lq * 8];
#pragma unroll
        for (int nt = 0; nt < 8; ++nt) {
#pragma unroll
            for (int r = 0; r < 4; ++r) acc[nt][r] *= alpha[r];
        }
#pragma unroll
        for (int nt = 0; nt < 8; ++nt)
            acc[nt] = __builtin_amdgcn_mfma_f32_16x16x32_bf16(pf, *(const short8*)&vfrag[nt][lane * 8], acc[nt], 0, 0, 0);
    }

    // epilogue: z[token][e*128 + p] = gate * O / l  (C-layout rows lq*4+r)
#pragma unroll
    for (int r = 0; r < 4; ++r) {
        const int tok = b * 1024 + s0 + 16 * w + lq * 4 + r;
        const int e = selidx[tok * 8 + h];
        const float g = selval[tok * 8 + h] / l_r[r];
        unsigned short* dst = zall + (size_t)tok * 2048 + e * 128 + lm;
#pragma unroll
        for (int nt = 0; nt < 8; ++nt)
            dst[nt * 16] = f2bf(acc[nt][r] * g);
    }
}

// ---------------- Kernel 6: out = z(4096x2048,bf16) @ out_proj(2048x1024) ----------------
__global__ __launch_bounds__(256) void k_out(const unsigned short* __restrict__ zall,
                                             const float* __restrict__ w_out,
                                             float* __restrict__ out) {
    __shared__ float ztile[64][64];    // 16 KB
    __shared__ float wtile[64][128];   // 32 KB
    const int t = threadIdx.x;
    const int tok0 = blockIdx.x * 64;
    const int o0 = blockIdx.y * 128;
    float acc[8][4];
#pragma unroll
    for (int k = 0; k < 8; ++k) { acc[k][0] = acc[k][1] = acc[k][2] = acc[k][3] = 0.f; }
    const int cr = t & 31, rr = t >> 5;
    for (int i0 = 0; i0 < 2048; i0 += 64) {
        __syncthreads();
        {
            const int r = t >> 2, c0 = (t & 3) * 16;
            const uint4* src = (const uint4*)(zall + (size_t)(tok0 + r) * 2048 + i0 + c0);
            const uint4 u0 = src[0], u1 = src[1];
            float* zp = &ztile[r][c0];
            zp[0]  = bf2f(u0.x); zp[1]  = bf2f(u0.x >> 16);
            zp[2]  = bf2f(u0.y); zp[3]  = bf2f(u0.y >> 16);
            zp[4]  = bf2f(u0.z); zp[5]  = bf2f(u0.z >> 16);
            zp[6]  = bf2f(u0.w); zp[7]  = bf2f(u0.w >> 16);
            zp[8]  = bf2f(u1.x); zp[9]  = bf2f(u1.x >> 16);
            zp[10] = bf2f(u1.y); zp[11] = bf2f(u1.y >> 16);
            zp[12] = bf2f(u1.z); zp[13] = bf2f(u1.z >> 16);
            zp[14] = bf2f(u1.w); zp[15] = bf2f(u1.w >> 16);
        }
#pragma unroll
        for (int l = 0; l < 8; ++l) {
            const int idx = t + 256 * l;
            const int r = idx >> 5, cc = idx & 31;
            ((float4*)&wtile[r][0])[cc] = ((const float4*)(w_out + (size_t)(i0 + r) * 1024 + o0))[cc];
        }
        __syncthreads();
        for (int i = 0; i < 64; ++i) {
            const float4 b4 = ((const float4*)&wtile[i][0])[cr];
#pragma unroll
            for (int k = 0; k < 8; ++k) {
                const float av = ztile[rr + 8 * k][i];
                acc[k][0] += av * b4.x; acc[k][1] += av * b4.y;
                acc[k][2] += av * b4.z; acc[k][3] += av * b4.w;
            }
        }
    }
#pragma unroll
    for (int k = 0; k < 8; ++k) {
        float4 o4; o4.x = acc[k][0]; o4.y = acc[k][1]; o4.z = acc[k][2]; o4.w = acc[k][3];
        *(float4*)(out + (size_t)(tok0 + rr + 8 * k) * 1024 + o0 + cr * 4) = o4;
    }
}

extern "C" void kernel_launch(void* const* d_in, const int* in_sizes, int n_in,
                              void* d_out, int out_size, void* d_ws, size_t ws_size,
                              hipStream_t stream) {
    const float* curr    = (const float*)d_in[0];  // (4,1024,1024)
    const float* attend  = (const float*)d_in[1];  // (4,1024,1024)
    const float* w_q     = (const float*)d_in[2];  // (16,1024,128)
    const float* w_kv    = (const float*)d_in[3];  // (1024,256)
    const float* w_out   = (const float*)d_in[4];  // (16,128,1024)
    const float* pos_pk  = (const float*)d_in[5];  // (128,1024)
    const float* sel_dst = (const float*)d_in[6];  // (16,1024)
    const float* scale   = (const float*)d_in[7];  // (1,)
    float* out = (float*)d_out;

    char* ws = (char*)d_ws;
    float* selval = (float*)ws;                                   // 131072 B
    int*   selidx = (int*)(ws + 131072);                          // 131072 B
    unsigned short* qall   = (unsigned short*)(ws + 262144);      // 16 MB
    unsigned short* zall   = qall + (size_t)8388608;              // 16 MB
    unsigned short* kfragg = zall + (size_t)8388608;              // 1 MB
    unsigned short* vfragg = kfragg + (size_t)524288;             // 1 MB
    unsigned short* kposfg = vfragg + (size_t)524288;             // 512 KB

    hipMemsetAsync(zall, 0, (size_t)8388608 * sizeof(unsigned short), stream);
    k_sel<<<4096, 256, 0, stream>>>(curr, sel_dst, selval, selidx);
    k_kv<<<256, 256, 0, stream>>>(attend, w_kv, scale, kfragg, vfragg);
    k_kpos<<<256, 128, 0, stream>>>(pos_pk, scale, kposfg);
    k_qall<<<dim3(64, 16), 256, 0, stream>>>(curr, w_q, scale, qall);
    k_attn<<<512, 256, 0, stream>>>(qall, kfragg, vfragg, kposfg, selidx, selval, zall);
    k_out<<<dim3(64, 8), 256, 0, stream>>>(zall, w_out, out);
}

// Round 3
// 382.214 us; speedup vs baseline: 4.8780x; 2.0339x over previous
//
#include <hip/hip_runtime.h>
#include <math.h>

// B=4 S=1024 D=1024 P=128 H=8 E=16, NT=4096, TPOS=2047

typedef __attribute__((ext_vector_type(8))) short short8;
typedef __attribute__((ext_vector_type(4))) float floatx4;

__device__ __forceinline__ float bf2f(unsigned int u) {
    union { unsigned int i; float f; } x; x.i = (u & 0xffffu) << 16; return x.f;
}
__device__ __forceinline__ unsigned short f2bf(float f) {
    union { float f; unsigned int i; } x; x.f = f;
    unsigned int r = x.i + 0x7fffu + ((x.i >> 16) & 1u);
    return (unsigned short)(r >> 16);
}

// async global->LDS: per-lane global addr, wave-uniform LDS base; lane data at base + lane*16
__device__ __forceinline__ void gload16(const void* g, void* l) {
    __builtin_amdgcn_global_load_lds(
        (const __attribute__((address_space(1))) unsigned int*)(uintptr_t)g,
        (__attribute__((address_space(3))) unsigned int*)(uintptr_t)l,
        16, 0, 0);
}

// Fragment layouts (16x16x32 bf16 MFMA), all HW-verified in R2:
//   A-frag (MxK):  afrag[m>>4][k>>5][((k&31)>>3)*16 + (m&15)][k&7]
//   B-frag (KxN):  bfrag[n>>4][k>>5][((k&31)>>3)*16 + (n&15)][k&7]
//   C/D:           col = lane&15, row = (lane>>4)*4 + reg

// ---------------- Kernel 1: selection scores + top-8 + sigmoid ----------------
__global__ __launch_bounds__(256) void k_sel(const float* __restrict__ curr,
                                             const float* __restrict__ sel_dst,
                                             float* __restrict__ selval,
                                             int* __restrict__ selidx) {
    __shared__ float row[1024];
    __shared__ float sel[16];
    const int token = blockIdx.x;
    const int t = threadIdx.x;
    ((float4*)row)[t] = ((const float4*)(curr + (size_t)token * 1024))[t];
    __syncthreads();
    const int wv = t >> 6, lane = t & 63;
    for (int e0 = 0; e0 < 4; ++e0) {
        const int e = wv * 4 + e0;
        const float* w = sel_dst + e * 1024;
        float p = 0.f;
        for (int i = lane; i < 1024; i += 64) p += row[i] * w[i];
        for (int off = 32; off; off >>= 1) p += __shfl_down(p, off, 64);
        if (lane == 0) sel[e] = p;
    }
    __syncthreads();
    if (t == 0) {
        float v[16];
#pragma unroll
        for (int e = 0; e < 16; ++e) v[e] = sel[e];
#pragma unroll
        for (int r = 0; r < 8; ++r) {
            int bi = 0; float bv = v[0];
#pragma unroll
            for (int e = 1; e < 16; ++e) { if (v[e] > bv) { bv = v[e]; bi = e; } }
            selidx[token * 8 + r] = bi;
            selval[token * 8 + r] = 1.f / (1.f + __expf(-bv));
            v[bi] = -INFINITY;
        }
    }
}

// ---------------- Kernel: activation f32 row-major (4096x1024) -> A-frag bf16 ----------------
__global__ __launch_bounds__(256) void k_conv_act(const float* __restrict__ src,
                                                  unsigned short* __restrict__ dst) {
    const int m = blockIdx.x;           // 0..4095
    const int t = threadIdx.x;          // 0..255, covers one row (k = 4t..4t+3)
    const float4 v = *(const float4*)(src + (size_t)m * 1024 + 4 * t);
    const int mt = m >> 4, kc = t >> 3;
    const int lane = ((t & 7) >> 1) * 16 + (m & 15);
    const size_t off = (((size_t)mt * 32 + kc) * 64 + lane) * 8 + 4 * (t & 1);
    uint2 o;
    o.x = (unsigned)f2bf(v.x) | ((unsigned)f2bf(v.y) << 16);
    o.y = (unsigned)f2bf(v.z) | ((unsigned)f2bf(v.w) << 16);
    *(uint2*)(dst + off) = o;
}

// ---------------- Kernel: weights f32 -> B-frag bf16 (w_q, w_out, w_kv) ----------------
__global__ __launch_bounds__(256) void k_conv_w(const float* __restrict__ w_q,
                                                const float* __restrict__ w_out,
                                                const float* __restrict__ w_kv,
                                                unsigned short* __restrict__ bfragq,
                                                unsigned short* __restrict__ bfragw,
                                                unsigned short* __restrict__ bfragkv) {
    const int bx = blockIdx.x;
    const int t = threadIdx.x;
    float v[4];
    if (bx < 2048) {
        // w_q: B[k=i][n=e*128+p], K=1024 (KC=32), N=2048
        const unsigned u = bx * 256 + t;
        const int p = u & 127, e = (u >> 7) & 15, kk = u >> 11;    // kk 0..255
#pragma unroll
        for (int d = 0; d < 4; ++d) v[d] = w_q[(size_t)e * 131072 + (size_t)(4 * kk + d) * 128 + p];
        const int n = e * 128 + p;
        const int nt = n >> 4, kc = kk >> 3;
        const int lane = ((kk & 7) >> 1) * 16 + (n & 15);
        const size_t off = (((size_t)nt * 32 + kc) * 64 + lane) * 8 + 4 * (kk & 1);
        uint2 o;
        o.x = (unsigned)f2bf(v[0]) | ((unsigned)f2bf(v[1]) << 16);
        o.y = (unsigned)f2bf(v[2]) | ((unsigned)f2bf(v[3]) << 16);
        *(uint2*)(bfragq + off) = o;
    } else if (bx < 4096) {
        // w_out: row-major 2048x1024, K=2048 (KC=64), N=1024
        const unsigned u = (bx - 2048) * 256 + t;
        const int n = ((bx & 3) * 256 + t) & 1023;
        const int kk = u >> 10;                                     // 0..511
#pragma unroll
        for (int d = 0; d < 4; ++d) v[d] = w_out[(size_t)(4 * kk + d) * 1024 + n];
        const int nt = n >> 4, kc = kk >> 3;
        const int lane = ((kk & 7) >> 1) * 16 + (n & 15);
        const size_t off = (((size_t)nt * 64 + kc) * 64 + lane) * 8 + 4 * (kk & 1);
        uint2 o;
        o.x = (unsigned)f2bf(v[0]) | ((unsigned)f2bf(v[1]) << 16);
        o.y = (unsigned)f2bf(v[2]) | ((unsigned)f2bf(v[3]) << 16);
        *(uint2*)(bfragw + off) = o;
    } else {
        // w_kv: row-major 1024x256, K=1024 (KC=32), N=256
        const int n = t;
        const int kk = bx - 4096;                                   // 0..255
#pragma unroll
        for (int d = 0; d < 4; ++d) v[d] = w_kv[(size_t)(4 * kk + d) * 256 + n];
        const int nt = n >> 4, kc = kk >> 3;
        const int lane = ((kk & 7) >> 1) * 16 + (n & 15);
        const size_t off = (((size_t)nt * 32 + kc) * 64 + lane) * 8 + 4 * (kk & 1);
        uint2 o;
        o.x = (unsigned)f2bf(v[0]) | ((unsigned)f2bf(v[1]) << 16);
        o.y = (unsigned)f2bf(v[2]) | ((unsigned)f2bf(v[3]) << 16);
        *(uint2*)(bfragkv + off) = o;
    }
}

// ---------------- Kernel 3: k_pos -> B-fragment layout (bf16) ----------------
__global__ __launch_bounds__(128) void k_kpos(const float* __restrict__ pos_pk,
                                              const float* __restrict__ scale,
                                              unsigned short* __restrict__ kposfg) {
    __shared__ float pe[8][1024];  // 32 KB
    const int t = threadIdx.x;     // 128 threads
    const int t0 = blockIdx.x * 8;
    const float c1 = -logf(10000.f) / 1024.f;
    for (int rr = 0; rr < 8; ++rr) {
        int tp = t0 + rr; if (tp > 2046) tp = 2046;
        const float pos = (float)(tp - 1023);
        for (int i = t; i < 512; i += 128) {
            const float dv = expf((2.f * (float)i) * c1);
            const float ang = pos * dv;
            pe[rr][2 * i]     = sinf(ang);
            pe[rr][2 * i + 1] = cosf(ang);
        }
    }
    __syncthreads();
    const float sc = sqrtf(scale[0]);
    float acc[8];
#pragma unroll
    for (int r = 0; r < 8; ++r) acc[r] = 0.f;
    const float* w = pos_pk + (size_t)t * 1024;  // row p=t of pos_to_pk
    for (int d = 0; d < 1024; ++d) {
        const float wv = w[d];
#pragma unroll
        for (int r = 0; r < 8; ++r) acc[r] += pe[r][d] * wv;
    }
    const int ch = t >> 5, pr = t & 31;
#pragma unroll
    for (int r = 0; r < 8; ++r) {
        const int tp = t0 + r;
        if (tp >= 2048) continue;
        const float v = (tp <= 2046) ? acc[r] * sc : 0.f;
        const size_t addr = (((size_t)(tp >> 4) * 4 + ch) * 64 + (pr >> 3) * 16 + (tp & 15)) * 8 + (pr & 7);
        kposfg[addr] = f2bf(v);
    }
}

// ---------------- Shared MFMA GEMM core: 128x128 tile, 4 waves, frag-ordered global in ----------------
__device__ __forceinline__ void gemm_frag_core(const unsigned short* __restrict__ Afrag,
                                               const unsigned short* __restrict__ Bfrag,
                                               int mt0, int nt0, int KC,
                                               unsigned short (*aT)[512],
                                               unsigned short (*bT)[512],
                                               floatx4 acc[4][4]) {
    const int t = threadIdx.x;
    const int w = t >> 6, lane = t & 63;
    const int wm = w >> 1, wn = w & 1;
    for (int kc = 0; kc < KC; ++kc) {
        __syncthreads();
        if (w < 2) {
#pragma unroll
            for (int li = 0; li < 4; ++li)
                gload16(Afrag + (((size_t)(mt0 + w * 4 + li) * KC + kc) * 64 + lane) * 8,
                        &aT[w * 4 + li][0]);
        } else {
#pragma unroll
            for (int li = 0; li < 4; ++li)
                gload16(Bfrag + (((size_t)(nt0 + (w - 2) * 4 + li) * KC + kc) * 64 + lane) * 8,
                        &bT[(w - 2) * 4 + li][0]);
        }
        __syncthreads();
        short8 af[4], bf[4];
#pragma unroll
        for (int i = 0; i < 4; ++i) af[i] = *(const short8*)&aT[wm * 4 + i][lane * 8];
#pragma unroll
        for (int j = 0; j < 4; ++j) bf[j] = *(const short8*)&bT[wn * 4 + j][lane * 8];
#pragma unroll
        for (int i = 0; i < 4; ++i)
#pragma unroll
            for (int j = 0; j < 4; ++j)
                acc[i][j] = __builtin_amdgcn_mfma_f32_16x16x32_bf16(af[i], bf[j], acc[i][j], 0, 0, 0);
    }
}

// ---------------- GEMM: qall = curr @ [w_q concat] * sc -> bf16 row-major 4096x2048 ----------------
__global__ __launch_bounds__(256) void k_gemm_qall(const unsigned short* __restrict__ Afrag,
                                                   const unsigned short* __restrict__ Bfrag,
                                                   const float* __restrict__ scale,
                                                   unsigned short* __restrict__ qall) {
    __shared__ __align__(16) unsigned short aT[8][512], bT[8][512];
    floatx4 acc[4][4];
#pragma unroll
    for (int i = 0; i < 4; ++i)
#pragma unroll
        for (int j = 0; j < 4; ++j) acc[i][j] = (floatx4){0.f, 0.f, 0.f, 0.f};
    gemm_frag_core(Afrag, Bfrag, blockIdx.x * 8, blockIdx.y * 8, 32, aT, bT, acc);
    const float sc = sqrtf(scale[0]);
    const int t = threadIdx.x, w = t >> 6, lane = t & 63;
    const int wm = w >> 1, wn = w & 1, lq = lane >> 4, lm = lane & 15;
    const int m0 = blockIdx.x * 128 + wm * 64, n0 = blockIdx.y * 128 + wn * 64;
#pragma unroll
    for (int i = 0; i < 4; ++i)
#pragma unroll
        for (int j = 0; j < 4; ++j)
#pragma unroll
            for (int r = 0; r < 4; ++r)
                qall[(size_t)(m0 + i * 16 + lq * 4 + r) * 2048 + n0 + j * 16 + lm] =
                    f2bf(acc[i][j][r] * sc);
}

// ---------------- GEMM: out = zfrag @ w_out -> f32 row-major 4096x1024 ----------------
__global__ __launch_bounds__(256) void k_gemm_out(const unsigned short* __restrict__ Afrag,
                                                  const unsigned short* __restrict__ Bfrag,
                                                  float* __restrict__ out) {
    __shared__ __align__(16) unsigned short aT[8][512], bT[8][512];
    floatx4 acc[4][4];
#pragma unroll
    for (int i = 0; i < 4; ++i)
#pragma unroll
        for (int j = 0; j < 4; ++j) acc[i][j] = (floatx4){0.f, 0.f, 0.f, 0.f};
    gemm_frag_core(Afrag, Bfrag, blockIdx.x * 8, blockIdx.y * 8, 64, aT, bT, acc);
    const int t = threadIdx.x, w = t >> 6, lane = t & 63;
    const int wm = w >> 1, wn = w & 1, lq = lane >> 4, lm = lane & 15;
    const int m0 = blockIdx.x * 128 + wm * 64, n0 = blockIdx.y * 128 + wn * 64;
#pragma unroll
    for (int i = 0; i < 4; ++i)
#pragma unroll
        for (int j = 0; j < 4; ++j)
#pragma unroll
            for (int r = 0; r < 4; ++r)
                out[(size_t)(m0 + i * 16 + lq * 4 + r) * 1024 + n0 + j * 16 + lm] = acc[i][j][r];
}

// ---------------- GEMM: kv = attend @ w_kv -> K/V B-fragment layouts (bf16) ----------------
__global__ __launch_bounds__(256) void k_gemm_kv(const unsigned short* __restrict__ Afrag,
                                                 const unsigned short* __restrict__ Bfrag,
                                                 const float* __restrict__ scale,
                                                 unsigned short* __restrict__ kfragg,
                                                 unsigned short* __restrict__ vfragg) {
    __shared__ __align__(16) unsigned short aT[8][512], bT[8][512];
    floatx4 acc[4][4];
#pragma unroll
    for (int i = 0; i < 4; ++i)
#pragma unroll
        for (int j = 0; j < 4; ++j) acc[i][j] = (floatx4){0.f, 0.f, 0.f, 0.f};
    gemm_frag_core(Afrag, Bfrag, blockIdx.x * 8, blockIdx.y * 8, 32, aT, bT, acc);
    const float sc = sqrtf(scale[0]);
    const int t = threadIdx.x, w = t >> 6, lane = t & 63;
    const int wm = w >> 1, wn = w & 1, lq = lane >> 4, lm = lane & 15;
    const int m0 = blockIdx.x * 128 + wm * 64, n0 = blockIdx.y * 128 + wn * 64;
#pragma unroll
    for (int i = 0; i < 4; ++i)
#pragma unroll
        for (int j = 0; j < 4; ++j) {
            const int n = n0 + j * 16 + lm;
#pragma unroll
            for (int r = 0; r < 4; ++r) {
                const int tok = m0 + i * 16 + lq * 4 + r;
                const int bb = tok >> 10, jj = tok & 1023;
                if (n < 128) {
                    const int p = n;
                    const size_t addr = ((((size_t)bb * 64 + (jj >> 4)) * 4 + (p >> 5)) * 64 +
                                         ((p & 31) >> 3) * 16 + (jj & 15)) * 8 + (p & 7);
                    kfragg[addr] = f2bf(acc[i][j][r] * sc);
                } else {
                    const int p = n - 128;
                    const size_t addr = ((((size_t)bb * 32 + (jj >> 5)) * 8 + (p >> 4)) * 64 +
                                         ((jj & 31) >> 3) * 16 + (p & 15)) * 8 + (jj & 7);
                    vfragg[addr] = f2bf(acc[i][j][r]);
                }
            }
        }
}

// ---------------- Kernel 5: MFMA flash attention with relative-position band ----------------
// grid: (b,h,s-tile of 64). 4 waves, wave w owns 16 s-rows [s0+16w, s0+16w+15].
__global__ __launch_bounds__(256) void k_attn(const unsigned short* __restrict__ qall,
                                              const unsigned short* __restrict__ kfragg,
                                              const unsigned short* __restrict__ vfragg,
                                              const unsigned short* __restrict__ kposfg,
                                              const int* __restrict__ selidx,
                                              const float* __restrict__ selval,
                                              unsigned short* __restrict__ zfrag) {
    __shared__ __align__(16) unsigned short kfrag[2][4][512];   // 8 KB
    __shared__ __align__(16) unsigned short vfrag[8][512];      // 8 KB
    __shared__ __align__(16) unsigned short kpfrag[6][4][512];  // 24 KB
    __shared__ __align__(16) float spos[4][16][52];             // 13.3 KB
    __shared__ __align__(16) unsigned short plds[4][16][56];    // 7 KB

    const int t = threadIdx.x;
    const int w = t >> 6, lane = t & 63;
    const int st = blockIdx.x & 15;
    const int bh = blockIdx.x >> 4;
    const int b = bh >> 3, h = bh & 7;
    const int s0 = st * 64;
    const int lq = lane >> 4;   // quad
    const int lm = lane & 15;

    // Q A-fragments: A[m=lm][k = c*32 + lq*8 + i]
    short8 qf[4];
    {
        const int token = b * 1024 + s0 + 16 * w + lm;
        const int e = selidx[token * 8 + h];
        const unsigned short* qb = qall + (size_t)token * 2048 + e * 128 + lq * 8;
#pragma unroll
        for (int c = 0; c < 4; ++c) qf[c] = *(const short8*)(qb + c * 32);
    }

    floatx4 acc[8];
#pragma unroll
    for (int nt = 0; nt < 8; ++nt) acc[nt] = (floatx4){0.f, 0.f, 0.f, 0.f};
    float m_r[4], l_r[4];
#pragma unroll
    for (int r = 0; r < 4; ++r) { m_r[r] = -INFINITY; l_r[r] = 0.f; }

    for (int j0 = 0; j0 < 1024; j0 += 32) {
        __syncthreads();   // previous iteration's fragment reads complete
        const int G0 = (j0 - s0 + 960) >> 4;   // base kpos subtile (always in [0,122])
        if (w < 3) {
#pragma unroll
            for (int s2 = 0; s2 < 2; ++s2) {
                const int stile = 2 * w + s2;
#pragma unroll
                for (int c = 0; c < 4; ++c)
                    gload16(kposfg + (((size_t)(G0 + stile) * 4 + c) * 64 + lane) * 8,
                            &kpfrag[stile][c][0]);
            }
        } else {
#pragma unroll
            for (int jt = 0; jt < 2; ++jt)
#pragma unroll
                for (int c = 0; c < 4; ++c)
                    gload16(kfragg + ((((size_t)b * 64 + (j0 >> 4) + jt) * 4 + c) * 64 + lane) * 8,
                            &kfrag[jt][c][0]);
#pragma unroll
            for (int nt = 0; nt < 8; ++nt)
                gload16(vfragg + ((((size_t)b * 32 + (j0 >> 5)) * 8 + nt) * 64 + lane) * 8,
                        &vfrag[nt][0]);
        }
        __syncthreads();   // vmcnt drained -> fragments visible

        // S_k = Q @ K^T  (two 16x16 j-subtiles)
        floatx4 sk0 = {0.f, 0.f, 0.f, 0.f}, sk1 = {0.f, 0.f, 0.f, 0.f};
#pragma unroll
        for (int c = 0; c < 4; ++c) {
            sk0 = __builtin_amdgcn_mfma_f32_16x16x32_bf16(qf[c], *(const short8*)&kfrag[0][c][lane * 8], sk0, 0, 0, 0);
            sk1 = __builtin_amdgcn_mfma_f32_16x16x32_bf16(qf[c], *(const short8*)&kfrag[1][c][lane * 8], sk1, 0, 0, 0);
        }
        // S_pos: wave w uses kpos subtile slots (3-w)..(5-w)
#pragma unroll
        for (int sp3 = 0; sp3 < 3; ++sp3) {
            floatx4 spv = {0.f, 0.f, 0.f, 0.f};
            const int slot = 3 - w + sp3;
#pragma unroll
            for (int c = 0; c < 4; ++c)
                spv = __builtin_amdgcn_mfma_f32_16x16x32_bf16(qf[c], *(const short8*)&kpfrag[slot][c][lane * 8], spv, 0, 0, 0);
#pragma unroll
            for (int r = 0; r < 4; ++r)
                spos[w][lq * 4 + r][sp3 * 16 + lm] = spv[r];
        }
        asm volatile("" ::: "memory");   // per-wave LDS RAW: keep program order

        // gather + combine + online softmax (C-layout rows lq*4+r, col lm)
        float alpha[4];
#pragma unroll
        for (int r = 0; r < 4; ++r) {
            const int row = lq * 4 + r;
            const float v0 = sk0[r] + spos[w][row][15 + lm - row];
            const float v1 = sk1[r] + spos[w][row][31 + lm - row];
            float mx = fmaxf(v0, v1);
            mx = fmaxf(mx, __shfl_xor(mx, 1, 64));
            mx = fmaxf(mx, __shfl_xor(mx, 2, 64));
            mx = fmaxf(mx, __shfl_xor(mx, 4, 64));
            mx = fmaxf(mx, __shfl_xor(mx, 8, 64));
            const float mn = fmaxf(m_r[r], mx);
            const float al = __expf(m_r[r] - mn);
            m_r[r] = mn;
            const float p0 = __expf(v0 - mn), p1 = __expf(v1 - mn);
            float rs = p0 + p1;
            rs += __shfl_xor(rs, 1, 64);
            rs += __shfl_xor(rs, 2, 64);
            rs += __shfl_xor(rs, 4, 64);
            rs += __shfl_xor(rs, 8, 64);
            l_r[r] = l_r[r] * al + rs;
            alpha[r] = al;
            plds[w][row][lm]      = f2bf(p0);
            plds[w][row][16 + lm] = f2bf(p1);
        }
        asm volatile("" ::: "memory");
        // P -> A-fragment; AV accumulate
        const short8 pf = *(const short8*)&plds[w][lm][lq * 8];
#pragma unroll
        for (int nt = 0; nt < 8; ++nt) {
#pragma unroll
            for (int r = 0; r < 4; ++r) acc[nt][r] *= alpha[r];
        }
#pragma unroll
        for (int nt = 0; nt < 8; ++nt)
            acc[nt] = __builtin_amdgcn_mfma_f32_16x16x32_bf16(pf, *(const short8*)&vfrag[nt][lane * 8], acc[nt], 0, 0, 0);
    }

    // epilogue: z -> A-fragment layout for the out GEMM (KC=64), zero elsewhere (memset)
#pragma unroll
    for (int r = 0; r < 4; ++r) {
        const int tok = b * 1024 + s0 + 16 * w + lq * 4 + r;
        const int e = selidx[tok * 8 + h];
        const float g = selval[tok * 8 + h] / l_r[r];
        const int mt = tok >> 4, tm = tok & 15;
#pragma unroll
        for (int nt = 0; nt < 8; ++nt) {
            const int k = e * 128 + nt * 16 + lm;
            const int kc = k >> 5;
            const int lane2 = (((k & 31) >> 3) << 4) + tm;
            zfrag[(((size_t)mt * 64 + kc) * 64 + lane2) * 8 + (k & 7)] = f2bf(acc[nt][r] * g);
        }
    }
}

extern "C" void kernel_launch(void* const* d_in, const int* in_sizes, int n_in,
                              void* d_out, int out_size, void* d_ws, size_t ws_size,
                              hipStream_t stream) {
    const float* curr    = (const float*)d_in[0];  // (4,1024,1024)
    const float* attend  = (const float*)d_in[1];  // (4,1024,1024)
    const float* w_q     = (const float*)d_in[2];  // (16,1024,128)
    const float* w_kv    = (const float*)d_in[3];  // (1024,256)
    const float* w_out   = (const float*)d_in[4];  // (16,128,1024)
    const float* pos_pk  = (const float*)d_in[5];  // (128,1024)
    const float* sel_dst = (const float*)d_in[6];  // (16,1024)
    const float* scale   = (const float*)d_in[7];  // (1,)
    float* out = (float*)d_out;

    char* ws = (char*)d_ws;
    float* selval = (float*)ws;                                        // 128 KB
    int*   selidx = (int*)(ws + 131072);                               // 128 KB
    unsigned short* kposfg  = (unsigned short*)(ws + 262144);          // 512 KB
    unsigned short* kfragg  = (unsigned short*)(ws + 786432);          // 1 MB
    unsigned short* vfragg  = (unsigned short*)(ws + 1835008);         // 1 MB
    unsigned short* bfragq  = (unsigned short*)(ws + 2883584);         // 4 MB
    unsigned short* bfragw  = (unsigned short*)(ws + 7077888);         // 4 MB
    unsigned short* bfragkv = (unsigned short*)(ws + 11272192);        // 512 KB
    unsigned short* afrag   = (unsigned short*)(ws + 11796480);        // 8 MB (curr, then attend)
    unsigned short* qall    = (unsigned short*)(ws + 20185088);        // 16 MB
    unsigned short* zfrag   = (unsigned short*)(ws + 36962304);        // 16 MB
    // total ~51.3 MB

    k_conv_w<<<4352, 256, 0, stream>>>(w_q, w_out, w_kv, bfragq, bfragw, bfragkv);
    k_conv_act<<<4096, 256, 0, stream>>>(curr, afrag);
    k_sel<<<4096, 256, 0, stream>>>(curr, sel_dst, selval, selidx);
    k_kpos<<<256, 128, 0, stream>>>(pos_pk, scale, kposfg);
    k_gemm_qall<<<dim3(32, 16), 256, 0, stream>>>(afrag, bfragq, scale, qall);
    k_conv_act<<<4096, 256, 0, stream>>>(attend, afrag);               // reuse afrag
    k_gemm_kv<<<dim3(32, 2), 256, 0, stream>>>(afrag, bfragkv, scale, kfragg, vfragg);
    hipMemsetAsync(zfrag, 0, (size_t)16777216, stream);
    k_attn<<<512, 256, 0, stream>>>(qall, kfragg, vfragg, kposfg, selidx, selval, zfrag);
    k_gemm_out<<<dim3(32, 8), 256, 0, stream>>>(zfrag, bfragw, out);
}

// Round 4
// 369.223 us; speedup vs baseline: 5.0497x; 1.0352x over previous
//
#include <hip/hip_runtime.h>
#include <math.h>

// B=4 S=1024 D=1024 P=128 H=8 E=16, NT=4096, TPOS=2047

typedef __attribute__((ext_vector_type(8))) short short8;
typedef __attribute__((ext_vector_type(4))) float floatx4;

__device__ __forceinline__ float bf2f(unsigned int u) {
    union { unsigned int i; float f; } x; x.i = (u & 0xffffu) << 16; return x.f;
}
__device__ __forceinline__ unsigned short f2bf(float f) {
    union { float f; unsigned int i; } x; x.f = f;
    unsigned int r = x.i + 0x7fffu + ((x.i >> 16) & 1u);
    return (unsigned short)(r >> 16);
}

// async global->LDS: per-lane global addr, wave-uniform LDS base; lane data at base + lane*16
__device__ __forceinline__ void gload16(const void* g, void* l) {
    __builtin_amdgcn_global_load_lds(
        (const __attribute__((address_space(1))) unsigned int*)(uintptr_t)g,
        (__attribute__((address_space(3))) unsigned int*)(uintptr_t)l,
        16, 0, 0);
}

// Fragment layouts (16x16x32 bf16 MFMA), all HW-verified in R2/R3:
//   A-frag (MxK):  afrag[m>>4][k>>5][((k&31)>>3)*16 + (m&15)][k&7]
//   B-frag (KxN):  bfrag[n>>4][k>>5][((k&31)>>3)*16 + (n&15)][k&7]
//   C/D:           col = lane&15, row = (lane>>4)*4 + reg
// A lane's 8 shorts sit at frag_base + lane*16B -> direct global_load_dwordx4 to VGPR.

// ---------------- Kernel 1: selection scores + top-8 + sigmoid ----------------
__global__ __launch_bounds__(256) void k_sel(const float* __restrict__ curr,
                                             const float* __restrict__ sel_dst,
                                             float* __restrict__ selval,
                                             int* __restrict__ selidx) {
    __shared__ float row[1024];
    __shared__ float sel[16];
    const int token = blockIdx.x;
    const int t = threadIdx.x;
    ((float4*)row)[t] = ((const float4*)(curr + (size_t)token * 1024))[t];
    __syncthreads();
    const int wv = t >> 6, lane = t & 63;
    for (int e0 = 0; e0 < 4; ++e0) {
        const int e = wv * 4 + e0;
        const float* w = sel_dst + e * 1024;
        float p = 0.f;
        for (int i = lane; i < 1024; i += 64) p += row[i] * w[i];
        for (int off = 32; off; off >>= 1) p += __shfl_down(p, off, 64);
        if (lane == 0) sel[e] = p;
    }
    __syncthreads();
    if (t == 0) {
        float v[16];
#pragma unroll
        for (int e = 0; e < 16; ++e) v[e] = sel[e];
#pragma unroll
        for (int r = 0; r < 8; ++r) {
            int bi = 0; float bv = v[0];
#pragma unroll
            for (int e = 1; e < 16; ++e) { if (v[e] > bv) { bv = v[e]; bi = e; } }
            selidx[token * 8 + r] = bi;
            selval[token * 8 + r] = 1.f / (1.f + __expf(-bv));
            v[bi] = -INFINITY;
        }
    }
}

// ---------------- Kernel: activation f32 row-major (4096x1024) -> A-frag bf16 ----------------
__global__ __launch_bounds__(256) void k_conv_act(const float* __restrict__ src,
                                                  unsigned short* __restrict__ dst) {
    const int m = blockIdx.x;           // 0..4095
    const int t = threadIdx.x;          // 0..255, covers one row (k = 4t..4t+3)
    const float4 v = *(const float4*)(src + (size_t)m * 1024 + 4 * t);
    const int mt = m >> 4, kc = t >> 3;
    const int lane = ((t & 7) >> 1) * 16 + (m & 15);
    const size_t off = (((size_t)mt * 32 + kc) * 64 + lane) * 8 + 4 * (t & 1);
    uint2 o;
    o.x = (unsigned)f2bf(v.x) | ((unsigned)f2bf(v.y) << 16);
    o.y = (unsigned)f2bf(v.z) | ((unsigned)f2bf(v.w) << 16);
    *(uint2*)(dst + off) = o;
}

// ---------------- Kernel: weights f32 -> B-frag bf16 (w_q, w_out, w_kv) ----------------
__global__ __launch_bounds__(256) void k_conv_w(const float* __restrict__ w_q,
                                                const float* __restrict__ w_out,
                                                const float* __restrict__ w_kv,
                                                unsigned short* __restrict__ bfragq,
                                                unsigned short* __restrict__ bfragw,
                                                unsigned short* __restrict__ bfragkv) {
    const int bx = blockIdx.x;
    const int t = threadIdx.x;
    float v[4];
    if (bx < 2048) {
        // w_q: B[k=i][n=e*128+p], K=1024 (KC=32), N=2048
        const unsigned u = bx * 256 + t;
        const int p = u & 127, e = (u >> 7) & 15, kk = u >> 11;    // kk 0..255
#pragma unroll
        for (int d = 0; d < 4; ++d) v[d] = w_q[(size_t)e * 131072 + (size_t)(4 * kk + d) * 128 + p];
        const int n = e * 128 + p;
        const int nt = n >> 4, kc = kk >> 3;
        const int lane = ((kk & 7) >> 1) * 16 + (n & 15);
        const size_t off = (((size_t)nt * 32 + kc) * 64 + lane) * 8 + 4 * (kk & 1);
        uint2 o;
        o.x = (unsigned)f2bf(v[0]) | ((unsigned)f2bf(v[1]) << 16);
        o.y = (unsigned)f2bf(v[2]) | ((unsigned)f2bf(v[3]) << 16);
        *(uint2*)(bfragq + off) = o;
    } else if (bx < 4096) {
        // w_out: row-major 2048x1024, K=2048 (KC=64), N=1024
        const unsigned u = (bx - 2048) * 256 + t;
        const int n = ((bx & 3) * 256 + t) & 1023;
        const int kk = u >> 10;                                     // 0..511
#pragma unroll
        for (int d = 0; d < 4; ++d) v[d] = w_out[(size_t)(4 * kk + d) * 1024 + n];
        const int nt = n >> 4, kc = kk >> 3;
        const int lane = ((kk & 7) >> 1) * 16 + (n & 15);
        const size_t off = (((size_t)nt * 64 + kc) * 64 + lane) * 8 + 4 * (kk & 1);
        uint2 o;
        o.x = (unsigned)f2bf(v[0]) | ((unsigned)f2bf(v[1]) << 16);
        o.y = (unsigned)f2bf(v[2]) | ((unsigned)f2bf(v[3]) << 16);
        *(uint2*)(bfragw + off) = o;
    } else {
        // w_kv: row-major 1024x256, K=1024 (KC=32), N=256
        const int n = t;
        const int kk = bx - 4096;                                   // 0..255
#pragma unroll
        for (int d = 0; d < 4; ++d) v[d] = w_kv[(size_t)(4 * kk + d) * 256 + n];
        const int nt = n >> 4, kc = kk >> 3;
        const int lane = ((kk & 7) >> 1) * 16 + (n & 15);
        const size_t off = (((size_t)nt * 32 + kc) * 64 + lane) * 8 + 4 * (kk & 1);
        uint2 o;
        o.x = (unsigned)f2bf(v[0]) | ((unsigned)f2bf(v[1]) << 16);
        o.y = (unsigned)f2bf(v[2]) | ((unsigned)f2bf(v[3]) << 16);
        *(uint2*)(bfragkv + off) = o;
    }
}

// ---------------- Kernel 3: k_pos -> B-fragment layout (bf16) ----------------
__global__ __launch_bounds__(128) void k_kpos(const float* __restrict__ pos_pk,
                                              const float* __restrict__ scale,
                                              unsigned short* __restrict__ kposfg) {
    __shared__ float pe[8][1024];  // 32 KB
    const int t = threadIdx.x;     // 128 threads
    const int t0 = blockIdx.x * 8;
    const float c1 = -logf(10000.f) / 1024.f;
    for (int rr = 0; rr < 8; ++rr) {
        int tp = t0 + rr; if (tp > 2046) tp = 2046;
        const float pos = (float)(tp - 1023);
        for (int i = t; i < 512; i += 128) {
            const float dv = expf((2.f * (float)i) * c1);
            const float ang = pos * dv;
            pe[rr][2 * i]     = sinf(ang);
            pe[rr][2 * i + 1] = cosf(ang);
        }
    }
    __syncthreads();
    const float sc = sqrtf(scale[0]);
    float acc[8];
#pragma unroll
    for (int r = 0; r < 8; ++r) acc[r] = 0.f;
    const float* w = pos_pk + (size_t)t * 1024;  // row p=t of pos_to_pk
    for (int d = 0; d < 1024; ++d) {
        const float wv = w[d];
#pragma unroll
        for (int r = 0; r < 8; ++r) acc[r] += pe[r][d] * wv;
    }
    const int ch = t >> 5, pr = t & 31;
#pragma unroll
    for (int r = 0; r < 8; ++r) {
        const int tp = t0 + r;
        if (tp >= 2048) continue;
        const float v = (tp <= 2046) ? acc[r] * sc : 0.f;
        const size_t addr = (((size_t)(tp >> 4) * 4 + ch) * 64 + (pr >> 3) * 16 + (tp & 15)) * 8 + (pr & 7);
        kposfg[addr] = f2bf(v);
    }
}

// ---------------- Shared MFMA GEMM core: 128x128 tile, 4 waves, frag-ordered global in ----------------
__device__ __forceinline__ void gemm_frag_core(const unsigned short* __restrict__ Afrag,
                                               const unsigned short* __restrict__ Bfrag,
                                               int mt0, int nt0, int KC,
                                               unsigned short (*aT)[512],
                                               unsigned short (*bT)[512],
                                               floatx4 acc[4][4]) {
    const int t = threadIdx.x;
    const int w = t >> 6, lane = t & 63;
    const int wm = w >> 1, wn = w & 1;
    for (int kc = 0; kc < KC; ++kc) {
        __syncthreads();
        if (w < 2) {
#pragma unroll
            for (int li = 0; li < 4; ++li)
                gload16(Afrag + (((size_t)(mt0 + w * 4 + li) * KC + kc) * 64 + lane) * 8,
                        &aT[w * 4 + li][0]);
        } else {
#pragma unroll
            for (int li = 0; li < 4; ++li)
                gload16(Bfrag + (((size_t)(nt0 + (w - 2) * 4 + li) * KC + kc) * 64 + lane) * 8,
                        &bT[(w - 2) * 4 + li][0]);
        }
        __syncthreads();
        short8 af[4], bf[4];
#pragma unroll
        for (int i = 0; i < 4; ++i) af[i] = *(const short8*)&aT[wm * 4 + i][lane * 8];
#pragma unroll
        for (int j = 0; j < 4; ++j) bf[j] = *(const short8*)&bT[wn * 4 + j][lane * 8];
#pragma unroll
        for (int i = 0; i < 4; ++i)
#pragma unroll
            for (int j = 0; j < 4; ++j)
                acc[i][j] = __builtin_amdgcn_mfma_f32_16x16x32_bf16(af[i], bf[j], acc[i][j], 0, 0, 0);
    }
}

// ---------------- GEMM: qall = curr @ [w_q concat] * sc -> bf16 row-major 4096x2048 ----------------
__global__ __launch_bounds__(256) void k_gemm_qall(const unsigned short* __restrict__ Afrag,
                                                   const unsigned short* __restrict__ Bfrag,
                                                   const float* __restrict__ scale,
                                                   unsigned short* __restrict__ qall) {
    __shared__ __align__(16) unsigned short aT[8][512], bT[8][512];
    floatx4 acc[4][4];
#pragma unroll
    for (int i = 0; i < 4; ++i)
#pragma unroll
        for (int j = 0; j < 4; ++j) acc[i][j] = (floatx4){0.f, 0.f, 0.f, 0.f};
    gemm_frag_core(Afrag, Bfrag, blockIdx.x * 8, blockIdx.y * 8, 32, aT, bT, acc);
    const float sc = sqrtf(scale[0]);
    const int t = threadIdx.x, w = t >> 6, lane = t & 63;
    const int wm = w >> 1, wn = w & 1, lq = lane >> 4, lm = lane & 15;
    const int m0 = blockIdx.x * 128 + wm * 64, n0 = blockIdx.y * 128 + wn * 64;
#pragma unroll
    for (int i = 0; i < 4; ++i)
#pragma unroll
        for (int j = 0; j < 4; ++j)
#pragma unroll
            for (int r = 0; r < 4; ++r)
                qall[(size_t)(m0 + i * 16 + lq * 4 + r) * 2048 + n0 + j * 16 + lm] =
                    f2bf(acc[i][j][r] * sc);
}

// ---------------- GEMM: out = zfrag @ w_out -> f32 row-major 4096x1024 ----------------
__global__ __launch_bounds__(256) void k_gemm_out(const unsigned short* __restrict__ Afrag,
                                                  const unsigned short* __restrict__ Bfrag,
                                                  float* __restrict__ out) {
    __shared__ __align__(16) unsigned short aT[8][512], bT[8][512];
    floatx4 acc[4][4];
#pragma unroll
    for (int i = 0; i < 4; ++i)
#pragma unroll
        for (int j = 0; j < 4; ++j) acc[i][j] = (floatx4){0.f, 0.f, 0.f, 0.f};
    gemm_frag_core(Afrag, Bfrag, blockIdx.x * 8, blockIdx.y * 8, 64, aT, bT, acc);
    const int t = threadIdx.x, w = t >> 6, lane = t & 63;
    const int wm = w >> 1, wn = w & 1, lq = lane >> 4, lm = lane & 15;
    const int m0 = blockIdx.x * 128 + wm * 64, n0 = blockIdx.y * 128 + wn * 64;
#pragma unroll
    for (int i = 0; i < 4; ++i)
#pragma unroll
        for (int j = 0; j < 4; ++j)
#pragma unroll
            for (int r = 0; r < 4; ++r)
                out[(size_t)(m0 + i * 16 + lq * 4 + r) * 1024 + n0 + j * 16 + lm] = acc[i][j][r];
}

// ---------------- GEMM: kv = attend @ w_kv -> K/V B-fragment layouts (bf16) ----------------
__global__ __launch_bounds__(256) void k_gemm_kv(const unsigned short* __restrict__ Afrag,
                                                 const unsigned short* __restrict__ Bfrag,
                                                 const float* __restrict__ scale,
                                                 unsigned short* __restrict__ kfragg,
                                                 unsigned short* __restrict__ vfragg) {
    __shared__ __align__(16) unsigned short aT[8][512], bT[8][512];
    floatx4 acc[4][4];
#pragma unroll
    for (int i = 0; i < 4; ++i)
#pragma unroll
        for (int j = 0; j < 4; ++j) acc[i][j] = (floatx4){0.f, 0.f, 0.f, 0.f};
    gemm_frag_core(Afrag, Bfrag, blockIdx.x * 8, blockIdx.y * 8, 32, aT, bT, acc);
    const float sc = sqrtf(scale[0]);
    const int t = threadIdx.x, w = t >> 6, lane = t & 63;
    const int wm = w >> 1, wn = w & 1, lq = lane >> 4, lm = lane & 15;
    const int m0 = blockIdx.x * 128 + wm * 64, n0 = blockIdx.y * 128 + wn * 64;
#pragma unroll
    for (int i = 0; i < 4; ++i)
#pragma unroll
        for (int j = 0; j < 4; ++j) {
            const int n = n0 + j * 16 + lm;
#pragma unroll
            for (int r = 0; r < 4; ++r) {
                const int tok = m0 + i * 16 + lq * 4 + r;
                const int bb = tok >> 10, jj = tok & 1023;
                if (n < 128) {
                    const int p = n;
                    const size_t addr = ((((size_t)bb * 64 + (jj >> 4)) * 4 + (p >> 5)) * 64 +
                                         ((p & 31) >> 3) * 16 + (jj & 15)) * 8 + (p & 7);
                    kfragg[addr] = f2bf(acc[i][j][r] * sc);
                } else {
                    const int p = n - 128;
                    const size_t addr = ((((size_t)bb * 32 + (jj >> 5)) * 8 + (p >> 4)) * 64 +
                                         ((jj & 31) >> 3) * 16 + (p & 15)) * 8 + (jj & 7);
                    vfragg[addr] = f2bf(acc[i][j][r]);
                }
            }
        }
}

// ---------------- Kernel 5: MFMA flash attention, register-direct fragments, barrier-free ----------------
// grid: (b,h,s-tile of 64). 4 waves, wave w owns 16 s-rows [s0+16w, s0+16w+15].
// All K/V/kpos fragments loaded global->VGPR directly (frag layout = lane*16B).
// spos/plds are per-wave LDS slices -> NO __syncthreads in this kernel.
__global__ __launch_bounds__(256) void k_attn(const unsigned short* __restrict__ qall,
                                              const unsigned short* __restrict__ kfragg,
                                              const unsigned short* __restrict__ vfragg,
                                              const unsigned short* __restrict__ kposfg,
                                              const int* __restrict__ selidx,
                                              const float* __restrict__ selval,
                                              unsigned short* __restrict__ zfrag) {
    __shared__ __align__(16) float spos[4][16][52];             // 13.3 KB
    __shared__ __align__(16) unsigned short plds[4][16][56];    // 7 KB

    const int t = threadIdx.x;
    const int w = t >> 6, lane = t & 63;
    const int st = blockIdx.x & 15;
    const int bh = blockIdx.x >> 4;
    const int b = bh >> 3, h = bh & 7;
    const int s0 = st * 64;
    const int lq = lane >> 4;   // quad
    const int lm = lane & 15;

    // Q A-fragments: A[m=lm][k = c*32 + lq*8 + i]
    short8 qf[4];
    {
        const int token = b * 1024 + s0 + 16 * w + lm;
        const int e = selidx[token * 8 + h];
        const unsigned short* qb = qall + (size_t)token * 2048 + e * 128 + lq * 8;
#pragma unroll
        for (int c = 0; c < 4; ++c) qf[c] = *(const short8*)(qb + c * 32);
    }
    // all-ones B-fragment: every column of the result equals the row-sum of P
    short8 onesf;
#pragma unroll
    for (int i = 0; i < 8; ++i) onesf[i] = (short)0x3F80;

    floatx4 acc[8], accl;
#pragma unroll
    for (int nt = 0; nt < 8; ++nt) acc[nt] = (floatx4){0.f, 0.f, 0.f, 0.f};
    accl = (floatx4){0.f, 0.f, 0.f, 0.f};
    float m_r[4];
#pragma unroll
    for (int r = 0; r < 4; ++r) m_r[r] = -INFINITY;

    for (int j0 = 0; j0 < 1024; j0 += 32) {
        // ---- direct VGPR fragment loads (all L2/L3-resident) ----
        short8 kf0[4], kf1[4];
        {
            const size_t kb0 = (((size_t)b * 64 + (j0 >> 4)) * 4) * 512;
#pragma unroll
            for (int c = 0; c < 4; ++c)
                kf0[c] = *(const short8*)(kfragg + kb0 + (size_t)c * 512 + lane * 8);
#pragma unroll
            for (int c = 0; c < 4; ++c)
                kf1[c] = *(const short8*)(kfragg + kb0 + (size_t)(4 + c) * 512 + lane * 8);
        }
        short8 kp[3][4];
        {
            const int g0 = ((j0 - s0 + 960) >> 4) + 3 - w;   // in [0,127]
#pragma unroll
            for (int sp = 0; sp < 3; ++sp)
#pragma unroll
                for (int c = 0; c < 4; ++c)
                    kp[sp][c] = *(const short8*)(kposfg + (((size_t)(g0 + sp) * 4 + c) * 64 + lane) * 8);
        }
        short8 vf[8];
        {
            const size_t vb = (((size_t)b * 32 + (j0 >> 5)) * 8) * 512;
#pragma unroll
            for (int nt = 0; nt < 8; ++nt)
                vf[nt] = *(const short8*)(vfragg + vb + (size_t)nt * 512 + lane * 8);
        }

        // ---- S_k = Q @ K^T (two 16x16 j-subtiles) ----
        floatx4 sk0 = {0.f, 0.f, 0.f, 0.f}, sk1 = {0.f, 0.f, 0.f, 0.f};
#pragma unroll
        for (int c = 0; c < 4; ++c) {
            sk0 = __builtin_amdgcn_mfma_f32_16x16x32_bf16(qf[c], kf0[c], sk0, 0, 0, 0);
            sk1 = __builtin_amdgcn_mfma_f32_16x16x32_bf16(qf[c], kf1[c], sk1, 0, 0, 0);
        }
        // ---- S_pos band (3 diagonal subtiles) ----
#pragma unroll
        for (int sp = 0; sp < 3; ++sp) {
            floatx4 spv = {0.f, 0.f, 0.f, 0.f};
#pragma unroll
            for (int c = 0; c < 4; ++c)
                spv = __builtin_amdgcn_mfma_f32_16x16x32_bf16(qf[c], kp[sp][c], spv, 0, 0, 0);
#pragma unroll
            for (int r = 0; r < 4; ++r)
                spos[w][lq * 4 + r][sp * 16 + lm] = spv[r];
        }
        asm volatile("" ::: "memory");   // per-wave LDS RAW: keep program order

        // ---- gather + combine + online softmax (C-layout rows lq*4+r, col lm) ----
        float alpha[4];
#pragma unroll
        for (int r = 0; r < 4; ++r) {
            const int row = lq * 4 + r;
            const float v0 = sk0[r] + spos[w][row][15 + lm - row];
            const float v1 = sk1[r] + spos[w][row][31 + lm - row];
            float mx = fmaxf(v0, v1);
            mx = fmaxf(mx, __shfl_xor(mx, 1, 64));
            mx = fmaxf(mx, __shfl_xor(mx, 2, 64));
            mx = fmaxf(mx, __shfl_xor(mx, 4, 64));
            mx = fmaxf(mx, __shfl_xor(mx, 8, 64));
            const float mn = fmaxf(m_r[r], mx);
            alpha[r] = __expf(m_r[r] - mn);
            m_r[r] = mn;
            plds[w][row][lm]      = f2bf(__expf(v0 - mn));
            plds[w][row][16 + lm] = f2bf(__expf(v1 - mn));
        }
        asm volatile("" ::: "memory");
        // ---- P -> A-fragment; AV accumulate (+ row-sum via ones column) ----
        const short8 pf = *(const short8*)&plds[w][lm][lq * 8];
#pragma unroll
        for (int nt = 0; nt < 8; ++nt) {
#pragma unroll
            for (int r = 0; r < 4; ++r) acc[nt][r] *= alpha[r];
        }
#pragma unroll
        for (int r = 0; r < 4; ++r) accl[r] *= alpha[r];
#pragma unroll
        for (int nt = 0; nt < 8; ++nt)
            acc[nt] = __builtin_amdgcn_mfma_f32_16x16x32_bf16(pf, vf[nt], acc[nt], 0, 0, 0);
        accl = __builtin_amdgcn_mfma_f32_16x16x32_bf16(pf, onesf, accl, 0, 0, 0);
    }

    // epilogue: z -> A-fragment layout for the out GEMM (KC=64), zero elsewhere (memset)
#pragma unroll
    for (int r = 0; r < 4; ++r) {
        const int tok = b * 1024 + s0 + 16 * w + lq * 4 + r;
        const int e = selidx[tok * 8 + h];
        const float g = selval[tok * 8 + h] / accl[r];
        const int mt = tok >> 4, tm = tok & 15;
#pragma unroll
        for (int nt = 0; nt < 8; ++nt) {
            const int k = e * 128 + nt * 16 + lm;
            const int kc = k >> 5;
            const int lane2 = (((k & 31) >> 3) << 4) + tm;
            zfrag[(((size_t)mt * 64 + kc) * 64 + lane2) * 8 + (k & 7)] = f2bf(acc[nt][r] * g);
        }
    }
}

extern "C" void kernel_launch(void* const* d_in, const int* in_sizes, int n_in,
                              void* d_out, int out_size, void* d_ws, size_t ws_size,
                              hipStream_t stream) {
    const float* curr    = (const float*)d_in[0];  // (4,1024,1024)
    const float* attend  = (const float*)d_in[1];  // (4,1024,1024)
    const float* w_q     = (const float*)d_in[2];  // (16,1024,128)
    const float* w_kv    = (const float*)d_in[3];  // (1024,256)
    const float* w_out   = (const float*)d_in[4];  // (16,128,1024)
    const float* pos_pk  = (const float*)d_in[5];  // (128,1024)
    const float* sel_dst = (const float*)d_in[6];  // (16,1024)
    const float* scale   = (const float*)d_in[7];  // (1,)
    float* out = (float*)d_out;

    char* ws = (char*)d_ws;
    float* selval = (float*)ws;                                        // 128 KB
    int*   selidx = (int*)(ws + 131072);                               // 128 KB
    unsigned short* kposfg  = (unsigned short*)(ws + 262144);          // 512 KB
    unsigned short* kfragg  = (unsigned short*)(ws + 786432);          // 1 MB
    unsigned short* vfragg  = (unsigned short*)(ws + 1835008);         // 1 MB
    unsigned short* bfragq  = (unsigned short*)(ws + 2883584);         // 4 MB
    unsigned short* bfragw  = (unsigned short*)(ws + 7077888);         // 4 MB
    unsigned short* bfragkv = (unsigned short*)(ws + 11272192);        // 512 KB
    unsigned short* afrag   = (unsigned short*)(ws + 11796480);        // 8 MB (curr, then attend)
    unsigned short* qall    = (unsigned short*)(ws + 20185088);        // 16 MB
    unsigned short* zfrag   = (unsigned short*)(ws + 36962304);        // 16 MB
    // total ~51.3 MB

    k_conv_w<<<4352, 256, 0, stream>>>(w_q, w_out, w_kv, bfragq, bfragw, bfragkv);
    k_conv_act<<<4096, 256, 0, stream>>>(curr, afrag);
    k_sel<<<4096, 256, 0, stream>>>(curr, sel_dst, selval, selidx);
    k_kpos<<<256, 128, 0, stream>>>(pos_pk, scale, kposfg);
    k_gemm_qall<<<dim3(32, 16), 256, 0, stream>>>(afrag, bfragq, scale, qall);
    k_conv_act<<<4096, 256, 0, stream>>>(attend, afrag);               // reuse afrag
    k_gemm_kv<<<dim3(32, 2), 256, 0, stream>>>(afrag, bfragkv, scale, kfragg, vfragg);
    hipMemsetAsync(zfrag, 0, (size_t)16777216, stream);
    k_attn<<<512, 256, 0, stream>>>(qall, kfragg, vfragg, kposfg, selidx, selval, zfrag);
    k_gemm_out<<<dim3(32, 8), 256, 0, stream>>>(zfrag, bfragw, out);
}

// Round 5
// 357.021 us; speedup vs baseline: 5.2223x; 1.0342x over previous
//
#include <hip/hip_runtime.h>
#include <math.h>

// B=4 S=1024 D=1024 P=128 H=8 E=16, NT=4096, TPOS=2047

typedef __attribute__((ext_vector_type(8))) short short8;
typedef __attribute__((ext_vector_type(4))) float floatx4;

__device__ __forceinline__ float bf2f(unsigned int u) {
    union { unsigned int i; float f; } x; x.i = (u & 0xffffu) << 16; return x.f;
}
__device__ __forceinline__ unsigned short f2bf(float f) {
    union { float f; unsigned int i; } x; x.f = f;
    unsigned int r = x.i + 0x7fffu + ((x.i >> 16) & 1u);
    return (unsigned short)(r >> 16);
}

// async global->LDS: per-lane global addr, wave-uniform LDS base; lane data at base + lane*16
__device__ __forceinline__ void gload16(const void* g, void* l) {
    __builtin_amdgcn_global_load_lds(
        (const __attribute__((address_space(1))) unsigned int*)(uintptr_t)g,
        (__attribute__((address_space(3))) unsigned int*)(uintptr_t)l,
        16, 0, 0);
}

// Fragment layouts (16x16x32 bf16 MFMA), all HW-verified in R2/R3:
//   A-frag (MxK):  afrag[m>>4][k>>5][((k&31)>>3)*16 + (m&15)][k&7]
//   B-frag (KxN):  bfrag[n>>4][k>>5][((k&31)>>3)*16 + (n&15)][k&7]
//   C/D:           col = lane&15, row = (lane>>4)*4 + reg
// A lane's 8 shorts sit at frag_base + lane*16B -> direct global_load_dwordx4 to VGPR.

// ---------------- Kernel 1: selection scores + top-8 + sigmoid ----------------
__global__ __launch_bounds__(256) void k_sel(const float* __restrict__ curr,
                                             const float* __restrict__ sel_dst,
                                             float* __restrict__ selval,
                                             int* __restrict__ selidx) {
    __shared__ float row[1024];
    __shared__ float sel[16];
    const int token = blockIdx.x;
    const int t = threadIdx.x;
    ((float4*)row)[t] = ((const float4*)(curr + (size_t)token * 1024))[t];
    __syncthreads();
    const int wv = t >> 6, lane = t & 63;
    for (int e0 = 0; e0 < 4; ++e0) {
        const int e = wv * 4 + e0;
        const float* w = sel_dst + e * 1024;
        float p = 0.f;
        for (int i = lane; i < 1024; i += 64) p += row[i] * w[i];
        for (int off = 32; off; off >>= 1) p += __shfl_down(p, off, 64);
        if (lane == 0) sel[e] = p;
    }
    __syncthreads();
    if (t == 0) {
        float v[16];
#pragma unroll
        for (int e = 0; e < 16; ++e) v[e] = sel[e];
#pragma unroll
        for (int r = 0; r < 8; ++r) {
            int bi = 0; float bv = v[0];
#pragma unroll
            for (int e = 1; e < 16; ++e) { if (v[e] > bv) { bv = v[e]; bi = e; } }
            selidx[token * 8 + r] = bi;
            selval[token * 8 + r] = 1.f / (1.f + __expf(-bv));
            v[bi] = -INFINITY;
        }
    }
}

// ---------------- Kernel: activation f32 row-major (4096x1024) -> A-frag bf16 ----------------
__global__ __launch_bounds__(256) void k_conv_act(const float* __restrict__ src,
                                                  unsigned short* __restrict__ dst) {
    const int m = blockIdx.x;           // 0..4095
    const int t = threadIdx.x;          // 0..255, covers one row (k = 4t..4t+3)
    const float4 v = *(const float4*)(src + (size_t)m * 1024 + 4 * t);
    const int mt = m >> 4, kc = t >> 3;
    const int lane = ((t & 7) >> 1) * 16 + (m & 15);
    const size_t off = (((size_t)mt * 32 + kc) * 64 + lane) * 8 + 4 * (t & 1);
    uint2 o;
    o.x = (unsigned)f2bf(v.x) | ((unsigned)f2bf(v.y) << 16);
    o.y = (unsigned)f2bf(v.z) | ((unsigned)f2bf(v.w) << 16);
    *(uint2*)(dst + off) = o;
}

// ---------------- Kernel: weights f32 -> B-frag bf16 (w_q, w_out, w_kv) ----------------
__global__ __launch_bounds__(256) void k_conv_w(const float* __restrict__ w_q,
                                                const float* __restrict__ w_out,
                                                const float* __restrict__ w_kv,
                                                unsigned short* __restrict__ bfragq,
                                                unsigned short* __restrict__ bfragw,
                                                unsigned short* __restrict__ bfragkv) {
    const int bx = blockIdx.x;
    const int t = threadIdx.x;
    float v[4];
    if (bx < 2048) {
        // w_q: B[k=i][n=e*128+p], K=1024 (KC=32), N=2048
        const unsigned u = bx * 256 + t;
        const int p = u & 127, e = (u >> 7) & 15, kk = u >> 11;    // kk 0..255
#pragma unroll
        for (int d = 0; d < 4; ++d) v[d] = w_q[(size_t)e * 131072 + (size_t)(4 * kk + d) * 128 + p];
        const int n = e * 128 + p;
        const int nt = n >> 4, kc = kk >> 3;
        const int lane = ((kk & 7) >> 1) * 16 + (n & 15);
        const size_t off = (((size_t)nt * 32 + kc) * 64 + lane) * 8 + 4 * (kk & 1);
        uint2 o;
        o.x = (unsigned)f2bf(v[0]) | ((unsigned)f2bf(v[1]) << 16);
        o.y = (unsigned)f2bf(v[2]) | ((unsigned)f2bf(v[3]) << 16);
        *(uint2*)(bfragq + off) = o;
    } else if (bx < 4096) {
        // w_out: row-major 2048x1024, K=2048 (KC=64), N=1024
        const unsigned u = (bx - 2048) * 256 + t;
        const int n = ((bx & 3) * 256 + t) & 1023;
        const int kk = u >> 10;                                     // 0..511
#pragma unroll
        for (int d = 0; d < 4; ++d) v[d] = w_out[(size_t)(4 * kk + d) * 1024 + n];
        const int nt = n >> 4, kc = kk >> 3;
        const int lane = ((kk & 7) >> 1) * 16 + (n & 15);
        const size_t off = (((size_t)nt * 64 + kc) * 64 + lane) * 8 + 4 * (kk & 1);
        uint2 o;
        o.x = (unsigned)f2bf(v[0]) | ((unsigned)f2bf(v[1]) << 16);
        o.y = (unsigned)f2bf(v[2]) | ((unsigned)f2bf(v[3]) << 16);
        *(uint2*)(bfragw + off) = o;
    } else {
        // w_kv: row-major 1024x256, K=1024 (KC=32), N=256
        const int n = t;
        const int kk = bx - 4096;                                   // 0..255
#pragma unroll
        for (int d = 0; d < 4; ++d) v[d] = w_kv[(size_t)(4 * kk + d) * 256 + n];
        const int nt = n >> 4, kc = kk >> 3;
        const int lane = ((kk & 7) >> 1) * 16 + (n & 15);
        const size_t off = (((size_t)nt * 32 + kc) * 64 + lane) * 8 + 4 * (kk & 1);
        uint2 o;
        o.x = (unsigned)f2bf(v[0]) | ((unsigned)f2bf(v[1]) << 16);
        o.y = (unsigned)f2bf(v[2]) | ((unsigned)f2bf(v[3]) << 16);
        *(uint2*)(bfragkv + off) = o;
    }
}

// ---------------- Kernel 3: k_pos -> B-fragment layout (bf16) ----------------
__global__ __launch_bounds__(128) void k_kpos(const float* __restrict__ pos_pk,
                                              const float* __restrict__ scale,
                                              unsigned short* __restrict__ kposfg) {
    __shared__ float pe[8][1024];  // 32 KB
    const int t = threadIdx.x;     // 128 threads
    const int t0 = blockIdx.x * 8;
    const float c1 = -logf(10000.f) / 1024.f;
    for (int rr = 0; rr < 8; ++rr) {
        int tp = t0 + rr; if (tp > 2046) tp = 2046;
        const float pos = (float)(tp - 1023);
        for (int i = t; i < 512; i += 128) {
            const float dv = expf((2.f * (float)i) * c1);
            const float ang = pos * dv;
            pe[rr][2 * i]     = sinf(ang);
            pe[rr][2 * i + 1] = cosf(ang);
        }
    }
    __syncthreads();
    const float sc = sqrtf(scale[0]);
    float acc[8];
#pragma unroll
    for (int r = 0; r < 8; ++r) acc[r] = 0.f;
    const float* w = pos_pk + (size_t)t * 1024;  // row p=t of pos_to_pk
    for (int d = 0; d < 1024; ++d) {
        const float wv = w[d];
#pragma unroll
        for (int r = 0; r < 8; ++r) acc[r] += pe[r][d] * wv;
    }
    const int ch = t >> 5, pr = t & 31;
#pragma unroll
    for (int r = 0; r < 8; ++r) {
        const int tp = t0 + r;
        if (tp >= 2048) continue;
        const float v = (tp <= 2046) ? acc[r] * sc : 0.f;
        const size_t addr = (((size_t)(tp >> 4) * 4 + ch) * 64 + (pr >> 3) * 16 + (tp & 15)) * 8 + (pr & 7);
        kposfg[addr] = f2bf(v);
    }
}

// ---------------- Shared MFMA GEMM core: 128x128 tile, 4 waves, frag-ordered global in ----------------
__device__ __forceinline__ void gemm_frag_core(const unsigned short* __restrict__ Afrag,
                                               const unsigned short* __restrict__ Bfrag,
                                               int mt0, int nt0, int KC,
                                               unsigned short (*aT)[512],
                                               unsigned short (*bT)[512],
                                               floatx4 acc[4][4]) {
    const int t = threadIdx.x;
    const int w = t >> 6, lane = t & 63;
    const int wm = w >> 1, wn = w & 1;
    for (int kc = 0; kc < KC; ++kc) {
        __syncthreads();
        if (w < 2) {
#pragma unroll
            for (int li = 0; li < 4; ++li)
                gload16(Afrag + (((size_t)(mt0 + w * 4 + li) * KC + kc) * 64 + lane) * 8,
                        &aT[w * 4 + li][0]);
        } else {
#pragma unroll
            for (int li = 0; li < 4; ++li)
                gload16(Bfrag + (((size_t)(nt0 + (w - 2) * 4 + li) * KC + kc) * 64 + lane) * 8,
                        &bT[(w - 2) * 4 + li][0]);
        }
        __syncthreads();
        short8 af[4], bf[4];
#pragma unroll
        for (int i = 0; i < 4; ++i) af[i] = *(const short8*)&aT[wm * 4 + i][lane * 8];
#pragma unroll
        for (int j = 0; j < 4; ++j) bf[j] = *(const short8*)&bT[wn * 4 + j][lane * 8];
#pragma unroll
        for (int i = 0; i < 4; ++i)
#pragma unroll
            for (int j = 0; j < 4; ++j)
                acc[i][j] = __builtin_amdgcn_mfma_f32_16x16x32_bf16(af[i], bf[j], acc[i][j], 0, 0, 0);
    }
}

// ---------------- GEMM: qall = curr @ [w_q concat] * sc -> bf16 row-major 4096x2048 ----------------
__global__ __launch_bounds__(256) void k_gemm_qall(const unsigned short* __restrict__ Afrag,
                                                   const unsigned short* __restrict__ Bfrag,
                                                   const float* __restrict__ scale,
                                                   unsigned short* __restrict__ qall) {
    __shared__ __align__(16) unsigned short aT[8][512], bT[8][512];
    floatx4 acc[4][4];
#pragma unroll
    for (int i = 0; i < 4; ++i)
#pragma unroll
        for (int j = 0; j < 4; ++j) acc[i][j] = (floatx4){0.f, 0.f, 0.f, 0.f};
    gemm_frag_core(Afrag, Bfrag, blockIdx.x * 8, blockIdx.y * 8, 32, aT, bT, acc);
    const float sc = sqrtf(scale[0]);
    const int t = threadIdx.x, w = t >> 6, lane = t & 63;
    const int wm = w >> 1, wn = w & 1, lq = lane >> 4, lm = lane & 15;
    const int m0 = blockIdx.x * 128 + wm * 64, n0 = blockIdx.y * 128 + wn * 64;
#pragma unroll
    for (int i = 0; i < 4; ++i)
#pragma unroll
        for (int j = 0; j < 4; ++j)
#pragma unroll
            for (int r = 0; r < 4; ++r)
                qall[(size_t)(m0 + i * 16 + lq * 4 + r) * 2048 + n0 + j * 16 + lm] =
                    f2bf(acc[i][j][r] * sc);
}

// ---------------- GEMM: out = zfrag @ w_out -> f32 row-major 4096x1024 ----------------
__global__ __launch_bounds__(256) void k_gemm_out(const unsigned short* __restrict__ Afrag,
                                                  const unsigned short* __restrict__ Bfrag,
                                                  float* __restrict__ out) {
    __shared__ __align__(16) unsigned short aT[8][512], bT[8][512];
    floatx4 acc[4][4];
#pragma unroll
    for (int i = 0; i < 4; ++i)
#pragma unroll
        for (int j = 0; j < 4; ++j) acc[i][j] = (floatx4){0.f, 0.f, 0.f, 0.f};
    gemm_frag_core(Afrag, Bfrag, blockIdx.x * 8, blockIdx.y * 8, 64, aT, bT, acc);
    const int t = threadIdx.x, w = t >> 6, lane = t & 63;
    const int wm = w >> 1, wn = w & 1, lq = lane >> 4, lm = lane & 15;
    const int m0 = blockIdx.x * 128 + wm * 64, n0 = blockIdx.y * 128 + wn * 64;
#pragma unroll
    for (int i = 0; i < 4; ++i)
#pragma unroll
        for (int j = 0; j < 4; ++j)
#pragma unroll
            for (int r = 0; r < 4; ++r)
                out[(size_t)(m0 + i * 16 + lq * 4 + r) * 1024 + n0 + j * 16 + lm] = acc[i][j][r];
}

// ---------------- GEMM: kv = attend @ w_kv -> K/V B-fragment layouts (bf16) ----------------
__global__ __launch_bounds__(256) void k_gemm_kv(const unsigned short* __restrict__ Afrag,
                                                 const unsigned short* __restrict__ Bfrag,
                                                 const float* __restrict__ scale,
                                                 unsigned short* __restrict__ kfragg,
                                                 unsigned short* __restrict__ vfragg) {
    __shared__ __align__(16) unsigned short aT[8][512], bT[8][512];
    floatx4 acc[4][4];
#pragma unroll
    for (int i = 0; i < 4; ++i)
#pragma unroll
        for (int j = 0; j < 4; ++j) acc[i][j] = (floatx4){0.f, 0.f, 0.f, 0.f};
    gemm_frag_core(Afrag, Bfrag, blockIdx.x * 8, blockIdx.y * 8, 32, aT, bT, acc);
    const float sc = sqrtf(scale[0]);
    const int t = threadIdx.x, w = t >> 6, lane = t & 63;
    const int wm = w >> 1, wn = w & 1, lq = lane >> 4, lm = lane & 15;
    const int m0 = blockIdx.x * 128 + wm * 64, n0 = blockIdx.y * 128 + wn * 64;
#pragma unroll
    for (int i = 0; i < 4; ++i)
#pragma unroll
        for (int j = 0; j < 4; ++j) {
            const int n = n0 + j * 16 + lm;
#pragma unroll
            for (int r = 0; r < 4; ++r) {
                const int tok = m0 + i * 16 + lq * 4 + r;
                const int bb = tok >> 10, jj = tok & 1023;
                if (n < 128) {
                    const int p = n;
                    const size_t addr = ((((size_t)bb * 64 + (jj >> 4)) * 4 + (p >> 5)) * 64 +
                                         ((p & 31) >> 3) * 16 + (jj & 15)) * 8 + (p & 7);
                    kfragg[addr] = f2bf(acc[i][j][r] * sc);
                } else {
                    const int p = n - 128;
                    const size_t addr = ((((size_t)bb * 32 + (jj >> 5)) * 8 + (p >> 4)) * 64 +
                                         ((jj & 31) >> 3) * 16 + (p & 15)) * 8 + (jj & 7);
                    vfragg[addr] = f2bf(acc[i][j][r]);
                }
            }
        }
}

// ---------------- k_attn R5: fixed-max softmax, bpermute band-gather, strength-reduced
//                  streams (+8192 B/iter), K-fragment register double-buffering ----------------
#define ATTN_FM 8.0f

__device__ __forceinline__ void attn_step(const char*& pk, const char*& pv, const char*& pp,
                                          short8 (&kf)[8], short8 (&kfN)[8],
                                          const short8 (&qf)[4], const short8& onesf,
                                          floatx4 (&acc)[8], floatx4& accl,
                                          unsigned short* __restrict__ pl,
                                          const int loff,
                                          const int (&baddr)[4], const int (&bsel)[4],
                                          const int lq, const int lm) {
    // issue all loads up front: current kpos + V, next-iteration K (prefetch)
    short8 kp[3][4];
#pragma unroll
    for (int sp = 0; sp < 3; ++sp)
#pragma unroll
        for (int c = 0; c < 4; ++c)
            kp[sp][c] = *(const short8*)(pp + sp * 4096 + c * 1024 + loff);
    short8 vf[8];
#pragma unroll
    for (int nt = 0; nt < 8; ++nt)
        vf[nt] = *(const short8*)(pv + nt * 1024 + loff);
#pragma unroll
    for (int q = 0; q < 8; ++q)
        kfN[q] = *(const short8*)(pk + 8192 + q * 1024 + loff);

    // S_k = Q @ K^T (two 16x16 j-subtiles) from current (pre-loaded) K frags
    floatx4 sk0 = {0.f, 0.f, 0.f, 0.f}, sk1 = {0.f, 0.f, 0.f, 0.f};
#pragma unroll
    for (int c = 0; c < 4; ++c) {
        sk0 = __builtin_amdgcn_mfma_f32_16x16x32_bf16(qf[c], kf[c], sk0, 0, 0, 0);
        sk1 = __builtin_amdgcn_mfma_f32_16x16x32_bf16(qf[c], kf[4 + c], sk1, 0, 0, 0);
    }
    // band: 3 diagonal subtiles
    floatx4 sp0 = {0.f, 0.f, 0.f, 0.f}, sp1 = {0.f, 0.f, 0.f, 0.f}, sp2 = {0.f, 0.f, 0.f, 0.f};
#pragma unroll
    for (int c = 0; c < 4; ++c) {
        sp0 = __builtin_amdgcn_mfma_f32_16x16x32_bf16(qf[c], kp[0][c], sp0, 0, 0, 0);
        sp1 = __builtin_amdgcn_mfma_f32_16x16x32_bf16(qf[c], kp[1][c], sp1, 0, 0, 0);
        sp2 = __builtin_amdgcn_mfma_f32_16x16x32_bf16(qf[c], kp[2][c], sp2, 0, 0, 0);
    }
    // diagonal gather via bpermute (reg-flow, no LDS) + fixed-max softmax
#pragma unroll
    for (int r = 0; r < 4; ++r) {
        const int a = baddr[r];
        const float b0 = __int_as_float(__builtin_amdgcn_ds_bpermute(a, __float_as_int(sp0[r])));
        const float b1 = __int_as_float(__builtin_amdgcn_ds_bpermute(a, __float_as_int(sp1[r])));
        const float b2 = __int_as_float(__builtin_amdgcn_ds_bpermute(a, __float_as_int(sp2[r])));
        const float v0 = sk0[r] + (bsel[r] ? b0 : b1);
        const float v1 = sk1[r] + (bsel[r] ? b1 : b2);
        pl[(lq * 4 + r) * 56 + lm]      = f2bf(__expf(v0 - ATTN_FM));
        pl[(lq * 4 + r) * 56 + 16 + lm] = f2bf(__expf(v1 - ATTN_FM));
    }
    asm volatile("" ::: "memory");   // per-wave LDS RAW ordering
    const short8 pf = *(const short8*)(pl + lm * 56 + lq * 8);
#pragma unroll
    for (int nt = 0; nt < 8; ++nt)
        acc[nt] = __builtin_amdgcn_mfma_f32_16x16x32_bf16(pf, vf[nt], acc[nt], 0, 0, 0);
    accl = __builtin_amdgcn_mfma_f32_16x16x32_bf16(pf, onesf, accl, 0, 0, 0);
    pk += 8192; pv += 8192; pp += 8192;
}

__global__ __launch_bounds__(256, 2) void k_attn(const unsigned short* __restrict__ qall,
                                                 const unsigned short* __restrict__ kfragg,
                                                 const unsigned short* __restrict__ vfragg,
                                                 const unsigned short* __restrict__ kposfg,
                                                 const int* __restrict__ selidx,
                                                 const float* __restrict__ selval,
                                                 unsigned short* __restrict__ zfrag) {
    __shared__ __align__(16) unsigned short plds[2][4][16][56];  // 14 KB, parity x wave

    const int t = threadIdx.x;
    const int w = t >> 6, lane = t & 63;
    const int st = blockIdx.x & 15;
    const int bh = blockIdx.x >> 4;
    const int b = bh >> 3, h = bh & 7;
    const int s0 = st * 64;
    const int lq = lane >> 4;
    const int lm = lane & 15;
    const int loff = lane * 16;

    // Q A-fragments
    short8 qf[4];
    {
        const int token = b * 1024 + s0 + 16 * w + lm;
        const int e = selidx[token * 8 + h];
        const unsigned short* qb = qall + (size_t)token * 2048 + e * 128 + lq * 8;
#pragma unroll
        for (int c = 0; c < 4; ++c) qf[c] = *(const short8*)(qb + c * 32);
    }
    short8 onesf;
#pragma unroll
    for (int i = 0; i < 8; ++i) onesf[i] = (short)0x3F80;

    // bpermute gather constants: c0 = 15 + lm - row, row = lq*4+r
    int baddr[4], bsel[4];
#pragma unroll
    for (int r = 0; r < 4; ++r) {
        const int c0 = 15 + lm - (lq * 4 + r);
        baddr[r] = (lq * 16 + (c0 & 15)) * 4;
        bsel[r] = (c0 < 16) ? 1 : 0;
    }

    floatx4 acc[8], accl;
#pragma unroll
    for (int nt = 0; nt < 8; ++nt) acc[nt] = (floatx4){0.f, 0.f, 0.f, 0.f};
    accl = (floatx4){0.f, 0.f, 0.f, 0.f};

    // stream pointers (constant +8192 B per iteration)
    const char* pk = (const char*)kfragg + (size_t)b * 262144;
    const char* pv = (const char*)vfragg + (size_t)b * 262144;
    const char* pp = (const char*)kposfg + ((size_t)(((960 - s0) >> 4) + 3 - w)) * 4096;

    short8 kfA[8], kfB[8];
#pragma unroll
    for (int q = 0; q < 8; ++q)
        kfA[q] = *(const short8*)(pk + q * 1024 + loff);

    unsigned short* pl0 = &plds[0][w][0][0];
    unsigned short* pl1 = &plds[1][w][0][0];
    for (int it2 = 0; it2 < 16; ++it2) {
        attn_step(pk, pv, pp, kfA, kfB, qf, onesf, acc, accl, pl0, loff, baddr, bsel, lq, lm);
        attn_step(pk, pv, pp, kfB, kfA, qf, onesf, acc, accl, pl1, loff, baddr, bsel, lq, lm);
    }
    // (last prefetch reads 8 KB past this batch's K stream -> still inside ws, discarded)

    // epilogue: z -> A-fragment layout for the out GEMM (KC=64), zero elsewhere (memset)
#pragma unroll
    for (int r = 0; r < 4; ++r) {
        const int tok = b * 1024 + s0 + 16 * w + lq * 4 + r;
        const int e = selidx[tok * 8 + h];
        const float g = selval[tok * 8 + h] / accl[r];
        const int mt = tok >> 4, tm = tok & 15;
#pragma unroll
        for (int nt = 0; nt < 8; ++nt) {
            const int k = e * 128 + nt * 16 + lm;
            const int kc = k >> 5;
            const int lane2 = (((k & 31) >> 3) << 4) + tm;
            zfrag[(((size_t)mt * 64 + kc) * 64 + lane2) * 8 + (k & 7)] = f2bf(acc[nt][r] * g);
        }
    }
}

extern "C" void kernel_launch(void* const* d_in, const int* in_sizes, int n_in,
                              void* d_out, int out_size, void* d_ws, size_t ws_size,
                              hipStream_t stream) {
    const float* curr    = (const float*)d_in[0];  // (4,1024,1024)
    const float* attend  = (const float*)d_in[1];  // (4,1024,1024)
    const float* w_q     = (const float*)d_in[2];  // (16,1024,128)
    const float* w_kv    = (const float*)d_in[3];  // (1024,256)
    const float* w_out   = (const float*)d_in[4];  // (16,128,1024)
    const float* pos_pk  = (const float*)d_in[5];  // (128,1024)
    const float* sel_dst = (const float*)d_in[6];  // (16,1024)
    const float* scale   = (const float*)d_in[7];  // (1,)
    float* out = (float*)d_out;

    char* ws = (char*)d_ws;
    float* selval = (float*)ws;                                        // 128 KB
    int*   selidx = (int*)(ws + 131072);                               // 128 KB
    unsigned short* kposfg  = (unsigned short*)(ws + 262144);          // 512 KB
    unsigned short* kfragg  = (unsigned short*)(ws + 786432);          // 1 MB
    unsigned short* vfragg  = (unsigned short*)(ws + 1835008);         // 1 MB
    unsigned short* bfragq  = (unsigned short*)(ws + 2883584);         // 4 MB
    unsigned short* bfragw  = (unsigned short*)(ws + 7077888);         // 4 MB
    unsigned short* bfragkv = (unsigned short*)(ws + 11272192);        // 512 KB
    unsigned short* afrag   = (unsigned short*)(ws + 11796480);        // 8 MB (curr, then attend)
    unsigned short* qall    = (unsigned short*)(ws + 20185088);        // 16 MB
    unsigned short* zfrag   = (unsigned short*)(ws + 36962304);        // 16 MB
    // total ~51.3 MB

    k_conv_w<<<4352, 256, 0, stream>>>(w_q, w_out, w_kv, bfragq, bfragw, bfragkv);
    k_conv_act<<<4096, 256, 0, stream>>>(curr, afrag);
    k_sel<<<4096, 256, 0, stream>>>(curr, sel_dst, selval, selidx);
    k_kpos<<<256, 128, 0, stream>>>(pos_pk, scale, kposfg);
    k_gemm_qall<<<dim3(32, 16), 256, 0, stream>>>(afrag, bfragq, scale, qall);
    k_conv_act<<<4096, 256, 0, stream>>>(attend, afrag);               // reuse afrag
    k_gemm_kv<<<dim3(32, 2), 256, 0, stream>>>(afrag, bfragkv, scale, kfragg, vfragg);
    hipMemsetAsync(zfrag, 0, (size_t)16777216, stream);
    k_attn<<<512, 256, 0, stream>>>(qall, kfragg, vfragg, kposfg, selidx, selval, zfrag);
    k_gemm_out<<<dim3(32, 8), 256, 0, stream>>>(zfrag, bfragw, out);
}